// Round 6
// baseline (5387.280 us; speedup 1.0000x reference)
//
#include <hip/hip_runtime.h>
#include <math.h>

// ---------------- problem constants ----------------
#define NB 8
#define NMELS 80
#define TT 512
#define NFREQ 401
#define NFFT 800
#define HOPSZ 200
#define NROWS (NB*TT)          // 4096 frames
#define LY 103000              // untrimmed istft length
#define LOUTW 102200
#define PADW 400
#define NSPEC (NROWS*NFREQ)    // 1640448
#define GLITERS 30
#define SGDITERS 50
#define SGD_SCALE 0.003125f    // 2/(B*n_mels)
#define K1P 832                // irfft GEMM K padded (26*32)
#define K2 800                 // rfft GEMM K (25*32)
#define N1P 896                // irfft GEMM N padded (7*128)
#define N2P 512                // rfft GEMM N padded
// scales: A x256, B1 x(800*16) [/800 dropped + 16], lo parts x2048
#define WSQ_SCALE 3276800.0f   // 800*16*256
#define LO_INV 4.8828125e-4f   // 2^-11

#define TWO_PI_D 6.283185307179586476925286766559

typedef _Float16 half8 __attribute__((ext_vector_type(8)));
typedef float f32x4 __attribute__((ext_vector_type(4)));

// ---------------- threefry2x32 (20 rounds) ----------------
__host__ __device__ inline void tf2x32(unsigned k0, unsigned k1,
                                       unsigned x0, unsigned x1,
                                       unsigned& o0, unsigned& o1) {
  unsigned ks0 = k0, ks1 = k1, ks2 = k0 ^ k1 ^ 0x1BD11BDAu;
  x0 += ks0; x1 += ks1;
#define TF_R(r) { x0 += x1; x1 = (x1 << (r)) | (x1 >> (32 - (r))); x1 ^= x0; }
  TF_R(13) TF_R(15) TF_R(26) TF_R(6)
  x0 += ks1; x1 += ks2 + 1u;
  TF_R(17) TF_R(29) TF_R(16) TF_R(24)
  x0 += ks2; x1 += ks0 + 2u;
  TF_R(13) TF_R(15) TF_R(26) TF_R(6)
  x0 += ks0; x1 += ks1 + 3u;
  TF_R(17) TF_R(29) TF_R(16) TF_R(24)
  x0 += ks1; x1 += ks2 + 4u;
  TF_R(13) TF_R(15) TF_R(26) TF_R(6)
  x0 += ks2; x1 += ks0 + 5u;
#undef TF_R
  o0 = x0; o1 = x1;
}

__device__ inline float u01(unsigned bits) {
  unsigned u = (bits >> 9) | 0x3f800000u;
  return __uint_as_float(u) - 1.0f;
}

__device__ inline int ang_map(int g) {
  int b = g / (NFREQ * TT);
  int r = g - b * (NFREQ * TT);
  int f = r / TT;
  int t = r - f * TT;
  return (b * TT + t) * NFREQ + f;
}

__global__ void k_rand_spec(unsigned ka, unsigned kb, float* __restrict__ spec) {
  int i = blockIdx.x * blockDim.x + threadIdx.x;
  if (i >= NSPEC) return;
  unsigned o0, o1; tf2x32(ka, kb, 0u, (unsigned)i, o0, o1);
  spec[i] = u01(o0 ^ o1);    // partitionable 32-bit fold
}

__global__ void k_rand_ang(unsigned kra, unsigned krb, unsigned kia, unsigned kib,
                           float* __restrict__ ar, float* __restrict__ ai) {
  int g = blockIdx.x * blockDim.x + threadIdx.x;
  if (g >= NSPEC) return;
  int d = ang_map(g);
  unsigned o0, o1;
  tf2x32(kra, krb, 0u, (unsigned)g, o0, o1); ar[d] = u01(o0 ^ o1);
  tf2x32(kia, kib, 0u, (unsigned)g, o0, o1); ai[d] = u01(o0 ^ o1);
}

// ---------------- mel filterbank ----------------
__device__ inline double mel2hz_d(double mel) {
  return 700.0 * (pow(10.0, mel / 2595.0) - 1.0);
}

__global__ void k_fb(float* __restrict__ fbT, int* __restrict__ fm0,
                     float* __restrict__ fw0, float* __restrict__ fw1) {
  int f = blockIdx.x * blockDim.x + threadIdx.x;
  if (f >= NFREQ) return;
  const double freq = 10.0 * (double)f;
  const double melmax = 2595.0 * log10(1.0 + 4000.0 / 700.0);
  const double step = melmax / 81.0;
  int first = -1; float w0v = 0.f, w1v = 0.f;
  double p0 = 0.0;
  double p1 = mel2hz_d(step);
  for (int m = 0; m < NMELS; ++m) {
    double m2 = (m + 2 == 81) ? melmax : (double)(m + 2) * step;
    double p2 = mel2hz_d(m2);
    double down = (freq - p0) / (p1 - p0);
    double up   = (p2 - freq) / (p2 - p1);
    double v = down < up ? down : up;
    if (v < 0.0) v = 0.0;
    float vf = (float)v;
    fbT[m * NFREQ + f] = vf;
    if (vf > 0.f) {
      if (first < 0) { first = m; w0v = vf; }
      else if (m == first + 1) { w1v = vf; }
    }
    p0 = p1; p1 = p2;
  }
  fm0[f] = first < 0 ? 0 : first;
  fw0[f] = first < 0 ? 0.f : w0v;
  fw1[f] = w1v;
}

__global__ void k_ranges(const float* __restrict__ fbT, int* __restrict__ mlo,
                         int* __restrict__ mhi) {
  int m = threadIdx.x;
  if (m >= NMELS) return;
  int lo = NFREQ, hi = 0;
  for (int f = 0; f < NFREQ; ++f)
    if (fbT[m * NFREQ + f] > 0.f) { if (lo == NFREQ) lo = f; hi = f + 1; }
  mlo[m] = lo; mhi[m] = hi < lo ? lo : hi;
}

// ---------------- window + OLA weight (pre-scaled) ----------------
__device__ inline double hann_d(int i) {
  return 0.5 - 0.5 * cos(TWO_PI_D * (double)i / 800.0);
}

__global__ void k_wsq(float* __restrict__ wsqs, float* __restrict__ win) {
  int j = blockIdx.x * blockDim.x + threadIdx.x;
  if (j >= LY) return;
  if (j < NFFT) win[j] = (float)hann_d(j);
  int t1 = j / HOPSZ; if (t1 > TT - 1) t1 = TT - 1;
  int t0 = (j - (NFFT - HOPSZ)) / HOPSZ; if (t0 < 0) t0 = 0;
  float s = 0.f;
  for (int t = t0; t <= t1; ++t) {
    float w = (float)hann_d(j - t * HOPSZ);
    s += w * w;
  }
  wsqs[j] = WSQ_SCALE * fmaxf(s, 1e-11f);
}

// ---------------- f16-split DFT tables ----------------
// B1 (irfft, transposed [n=time][kk=freq-row]), scaled x16, /800 dropped
__global__ void k_tabs1(_Float16* __restrict__ Bh, _Float16* __restrict__ Bl) {
  int idx = blockIdx.x * blockDim.x + threadIdx.x;
  if (idx >= N1P * K1P) return;
  int n = idx / K1P, kk = idx - n * K1P;
  double v = 0.0;
  if (n < NFFT && kk < 802) {
    double wn = hann_d(n);
    if (kk < NFREQ) {
      int k = kk;
      double ak = (k == 0 || k == 400) ? 1.0 : 2.0;
      int ph = (k * n) % NFFT;
      v = 16.0 * ak * cos((double)ph * (TWO_PI_D / 800.0)) * wn;
    } else {
      int k = kk - NFREQ;
      if (k != 0 && k != 400) {
        int ph = (k * n) % NFFT;
        v = 16.0 * (-2.0) * sin((double)ph * (TWO_PI_D / 800.0)) * wn;
      }
    }
  }
  float vf = (float)v;
  _Float16 h = (_Float16)vf;
  Bh[idx] = h;
  Bl[idx] = (_Float16)((vf - (float)h) * 2048.0f);
}

// B2 (rfft, transposed [n=freq-col][k=time]): cos and -sin
__global__ void k_tabs2(_Float16* __restrict__ Bch, _Float16* __restrict__ Bcl,
                        _Float16* __restrict__ Bsh, _Float16* __restrict__ Bsl) {
  int idx = blockIdx.x * blockDim.x + threadIdx.x;
  if (idx >= N2P * K2) return;
  int n = idx / K2, k = idx - n * K2;
  double c = 0.0, s = 0.0;
  if (n < NFREQ) {
    int ph = (n * k) % NFFT;
    double ang = (double)ph * (TWO_PI_D / 800.0);
    c = cos(ang); s = -sin(ang);
  }
  float cf = (float)c, sf = (float)s;
  _Float16 ch = (_Float16)cf, sh = (_Float16)sf;
  Bch[idx] = ch; Bcl[idx] = (_Float16)((cf - (float)ch) * 2048.0f);
  Bsh[idx] = sh; Bsl[idx] = (_Float16)((sf - (float)sh) * 2048.0f);
}

// ---------------- InverseMelScale: 50 SGD iterations in-kernel ----------------
__global__ __launch_bounds__(128) void k_sgd(
    const float* __restrict__ spec0, const float* __restrict__ xmel,
    const float* __restrict__ fbT, const int* __restrict__ mlo,
    const int* __restrict__ mhi, const int* __restrict__ fm0,
    const float* __restrict__ fw0, const float* __restrict__ fw1,
    float* __restrict__ mag) {
  __shared__ float s_spec[NFREQ], s_vel[NFREQ], s_diff[NMELS], s_mel[NMELS];
  const int row = blockIdx.x;
  const int b = row / TT, t = row - b * TT;
  const int tid = threadIdx.x;
  for (int f = tid; f < NFREQ; f += 128) { s_spec[f] = spec0[row * NFREQ + f]; s_vel[f] = 0.f; }
  if (tid < NMELS) s_mel[tid] = xmel[(b * NMELS + tid) * TT + t];
  __syncthreads();
  for (int it = 0; it < SGDITERS; ++it) {
    if (tid < NMELS) {
      float acc = 0.f;
      const int lo = mlo[tid], hi = mhi[tid];
      const float* fr = fbT + tid * NFREQ;
      for (int f = lo; f < hi; ++f) acc = fmaf(s_spec[f], fr[f], acc);
      s_diff[tid] = s_mel[tid] - acc;
    }
    __syncthreads();
    for (int f = tid; f < NFREQ; f += 128) {
      int m0 = fm0[f];
      int m1 = m0 + 1; if (m1 > NMELS - 1) m1 = NMELS - 1;
      float d = s_diff[m0] * fw0[f] + s_diff[m1] * fw1[f];
      float g = -SGD_SCALE * d;
      float v = 0.9f * s_vel[f] + g;
      s_vel[f] = v;
      float sp = s_spec[f] - 0.1f * v;
      s_spec[f] = sp > 0.f ? sp : 0.f;
    }
    __syncthreads();
  }
  for (int f = tid; f < NFREQ; f += 128) mag[row * NFREQ + f] = sqrtf(s_spec[f]);
}

// ---------------- A1 prep for iteration 0 only ----------------
__global__ void k_prep1(const float* __restrict__ mag, const float* __restrict__ ar,
                        const float* __restrict__ ai,
                        _Float16* __restrict__ Ah, _Float16* __restrict__ Al) {
  int kk = blockIdx.x * 256 + threadIdx.x;
  if (kk >= K1P) return;
  int row = blockIdx.y;
  float v = 0.f;
  if (kk < 802) {
    int k = (kk < NFREQ) ? kk : kk - NFREQ;
    int gi = row * NFREQ + k;
    float aa = (kk < NFREQ) ? ar[gi] : ai[gi];
    v = mag[gi] * aa * 256.0f;
  }
  _Float16 h = (_Float16)v;
  size_t o = (size_t)row * K1P + kk;
  Ah[o] = h;
  Al[o] = (_Float16)((v - (float)h) * 2048.0f);
}

// ---------------- MFMA split-f16 GEMM 1: frames = A1 @ B1 ----------------
// 32(M) x 128(N) tile, 2 waves each 32x64; grid (7, 128)
__global__ __launch_bounds__(128, 3) void k_mm1(
    const _Float16* __restrict__ Ah, const _Float16* __restrict__ Al,
    const _Float16* __restrict__ Bh, const _Float16* __restrict__ Bl,
    float* __restrict__ frames) {
  __shared__ __align__(16) _Float16 As_h[32 * 40], As_l[32 * 40];
  __shared__ __align__(16) _Float16 Bs_h[128 * 40], Bs_l[128 * 40];
  const int t = threadIdx.x;
  const int row0 = blockIdx.y * 32;
  const int col0 = blockIdx.x * 128;
  const int ar_ = t >> 2, ak_ = (t & 3) * 8;
  const int lane = t & 63, wn = t >> 6;
  const int lm = lane & 15, qd = lane >> 4;
  f32x4 acc0[2][4] = {}, acc1[2][4] = {};
  const size_t abase = (size_t)(row0 + ar_) * K1P;
  const size_t bbase = (size_t)(col0 + t) * K1P;
  for (int k0 = 0; k0 < K1P; k0 += 32) {
    *(uint4*)&As_h[ar_ * 40 + ak_] = *(const uint4*)&Ah[abase + k0 + ak_];
    *(uint4*)&As_l[ar_ * 40 + ak_] = *(const uint4*)&Al[abase + k0 + ak_];
#pragma unroll
    for (int q = 0; q < 4; ++q) {
      *(uint4*)&Bs_h[t * 40 + q * 8] = *(const uint4*)&Bh[bbase + k0 + q * 8];
      *(uint4*)&Bs_l[t * 40 + q * 8] = *(const uint4*)&Bl[bbase + k0 + q * 8];
    }
    __syncthreads();
    half8 a_h[2], a_l[2];
#pragma unroll
    for (int i = 0; i < 2; ++i) {
      int m = i * 16 + lm;
      a_h[i] = *(const half8*)&As_h[m * 40 + qd * 8];
      a_l[i] = *(const half8*)&As_l[m * 40 + qd * 8];
    }
#pragma unroll
    for (int j = 0; j < 4; ++j) {
      int n = wn * 64 + j * 16 + lm;
      half8 b_h = *(const half8*)&Bs_h[n * 40 + qd * 8];
      half8 b_l = *(const half8*)&Bs_l[n * 40 + qd * 8];
#pragma unroll
      for (int i = 0; i < 2; ++i) {
        acc0[i][j] = __builtin_amdgcn_mfma_f32_16x16x32_f16(a_h[i], b_h, acc0[i][j], 0, 0, 0);
        acc1[i][j] = __builtin_amdgcn_mfma_f32_16x16x32_f16(a_h[i], b_l, acc1[i][j], 0, 0, 0);
        acc1[i][j] = __builtin_amdgcn_mfma_f32_16x16x32_f16(a_l[i], b_h, acc1[i][j], 0, 0, 0);
      }
    }
    __syncthreads();
  }
#pragma unroll
  for (int j = 0; j < 4; ++j) {
    int col = col0 + wn * 64 + j * 16 + lm;
    if (col < NFFT) {
#pragma unroll
      for (int i = 0; i < 2; ++i)
#pragma unroll
        for (int r = 0; r < 4; ++r) {
          int row = row0 + i * 16 + qd * 4 + r;
          frames[(size_t)row * NFFT + col] = acc0[i][j][r] + acc1[i][j][r] * LO_INV;
        }
    }
  }
}

// ---------------- fused OLA + window + split-A2 (in-loop) ----------------
__global__ void k_olaprep(const float* __restrict__ frames, const float* __restrict__ wsqs,
                          const float* __restrict__ win,
                          _Float16* __restrict__ A2h, _Float16* __restrict__ A2l) {
  int idx = blockIdx.x * 256 + threadIdx.x;     // row*800 + k
  if (idx >= NROWS * K2) return;
  int row = idx / K2, k = idx - row * K2;
  int b = row >> 9, tt = row & 511;
  int j = tt * HOPSZ + k;
  int jm = (j < PADW) ? (NFFT - j) : ((j < PADW + LOUTW) ? j : (205198 - j));
  int t1 = jm / HOPSZ; if (t1 > TT - 1) t1 = TT - 1;
  int t0 = (jm - (NFFT - HOPSZ)) / HOPSZ; if (t0 < 0) t0 = 0;
  const float* fb_ = frames + (size_t)b * TT * NFFT;
  float s = 0.f;
  for (int t = t0; t <= t1; ++t) s += fb_[t * NFFT + (jm - t * HOPSZ)];
  float y = s / wsqs[jm];                       // == reference y[jm] (unit scale)
  float v = y * win[k] * 256.0f;
  _Float16 h = (_Float16)v;
  A2h[idx] = h;
  A2l[idx] = (_Float16)((v - (float)h) * 2048.0f);
}

// ---------------- MFMA split-f16 GEMM 2: rfft + momentum + normalize + A1' ----------------
// 32(M) x 64(N) tile, 2 waves each 32x32; grid (7, 128)
__global__ __launch_bounds__(128, 3) void k_mm2(
    const _Float16* __restrict__ Ah, const _Float16* __restrict__ Al,
    const _Float16* __restrict__ Bch, const _Float16* __restrict__ Bcl,
    const _Float16* __restrict__ Bsh, const _Float16* __restrict__ Bsl,
    const float* __restrict__ mag,
    float* __restrict__ tppr, float* __restrict__ tppi,
    _Float16* __restrict__ A1h, _Float16* __restrict__ A1l, float beta) {
  __shared__ __align__(16) _Float16 As_h[32 * 40], As_l[32 * 40];
  __shared__ __align__(16) _Float16 Bc_h[64 * 40], Bc_l[64 * 40];
  __shared__ __align__(16) _Float16 Bn_h[64 * 40], Bn_l[64 * 40];
  const int t = threadIdx.x;
  const int row0 = blockIdx.y * 32;
  const int col0 = blockIdx.x * 64;
  const int ar_ = t >> 2, ak_ = (t & 3) * 8;
  const int bn_ = t >> 1, bo_ = (t & 1) * 16;
  const int lane = t & 63, wn = t >> 6;
  const int lm = lane & 15, qd = lane >> 4;
  f32x4 cr0[2][2] = {}, cr1[2][2] = {}, ci0[2][2] = {}, ci1[2][2] = {};
  const size_t abase = (size_t)(row0 + ar_) * K2;
  const size_t bbase = (size_t)(col0 + bn_) * K2;
  for (int k0 = 0; k0 < K2; k0 += 32) {
    *(uint4*)&As_h[ar_ * 40 + ak_] = *(const uint4*)&Ah[abase + k0 + ak_];
    *(uint4*)&As_l[ar_ * 40 + ak_] = *(const uint4*)&Al[abase + k0 + ak_];
#pragma unroll
    for (int q = 0; q < 2; ++q) {
      int o = bo_ + q * 8;
      *(uint4*)&Bc_h[bn_ * 40 + o] = *(const uint4*)&Bch[bbase + k0 + o];
      *(uint4*)&Bc_l[bn_ * 40 + o] = *(const uint4*)&Bcl[bbase + k0 + o];
      *(uint4*)&Bn_h[bn_ * 40 + o] = *(const uint4*)&Bsh[bbase + k0 + o];
      *(uint4*)&Bn_l[bn_ * 40 + o] = *(const uint4*)&Bsl[bbase + k0 + o];
    }
    __syncthreads();
    half8 a_h[2], a_l[2];
#pragma unroll
    for (int i = 0; i < 2; ++i) {
      int m = i * 16 + lm;
      a_h[i] = *(const half8*)&As_h[m * 40 + qd * 8];
      a_l[i] = *(const half8*)&As_l[m * 40 + qd * 8];
    }
#pragma unroll
    for (int j = 0; j < 2; ++j) {
      int n = wn * 32 + j * 16 + lm;
      half8 bc_h = *(const half8*)&Bc_h[n * 40 + qd * 8];
      half8 bc_l = *(const half8*)&Bc_l[n * 40 + qd * 8];
      half8 bs_h = *(const half8*)&Bn_h[n * 40 + qd * 8];
      half8 bs_l = *(const half8*)&Bn_l[n * 40 + qd * 8];
#pragma unroll
      for (int i = 0; i < 2; ++i) {
        cr0[i][j] = __builtin_amdgcn_mfma_f32_16x16x32_f16(a_h[i], bc_h, cr0[i][j], 0, 0, 0);
        cr1[i][j] = __builtin_amdgcn_mfma_f32_16x16x32_f16(a_h[i], bc_l, cr1[i][j], 0, 0, 0);
        cr1[i][j] = __builtin_amdgcn_mfma_f32_16x16x32_f16(a_l[i], bc_h, cr1[i][j], 0, 0, 0);
        ci0[i][j] = __builtin_amdgcn_mfma_f32_16x16x32_f16(a_h[i], bs_h, ci0[i][j], 0, 0, 0);
        ci1[i][j] = __builtin_amdgcn_mfma_f32_16x16x32_f16(a_h[i], bs_l, ci1[i][j], 0, 0, 0);
        ci1[i][j] = __builtin_amdgcn_mfma_f32_16x16x32_f16(a_l[i], bs_h, ci1[i][j], 0, 0, 0);
      }
    }
    __syncthreads();
  }
#pragma unroll
  for (int j = 0; j < 2; ++j) {
    int col = col0 + wn * 32 + j * 16 + lm;
    if (col < NFREQ) {
#pragma unroll
      for (int i = 0; i < 2; ++i)
#pragma unroll
        for (int r = 0; r < 4; ++r) {
          int row = row0 + i * 16 + qd * 4 + r;
          int idx = row * NFREQ + col;
          float rr = cr0[i][j][r] + cr1[i][j][r] * LO_INV;   // (x256-scaled rebuilt)
          float ri = ci0[i][j][r] + ci1[i][j][r] * LO_INV;
          float nr = rr - beta * tppr[idx];
          float ni = ri - beta * tppi[idx];
          tppr[idx] = rr; tppi[idx] = ri;
          float den = sqrtf(nr * nr + ni * ni) + 1e-16f;
          float arv = nr / den, aiv = ni / den;
          // fused next-iteration A1 = mag * ang * 256 (split f16)
          float mg = mag[idx] * 256.0f;
          size_t ab = (size_t)row * K1P;
          float v1 = mg * arv;
          _Float16 h1 = (_Float16)v1;
          A1h[ab + col] = h1;
          A1l[ab + col] = (_Float16)((v1 - (float)h1) * 2048.0f);
          float v2 = mg * aiv;
          _Float16 h2 = (_Float16)v2;
          A1h[ab + NFREQ + col] = h2;
          A1l[ab + NFREQ + col] = (_Float16)((v2 - (float)h2) * 2048.0f);
        }
    }
  }
}

// ---------------- final overlap-add (full y, once) ----------------
__global__ void k_ola(const float* __restrict__ frames, const float* __restrict__ wsqs,
                      float* __restrict__ y) {
  int idx = blockIdx.x * blockDim.x + threadIdx.x;
  if (idx >= NB * LY) return;
  int b = idx / LY, j = idx - b * LY;
  int t1 = j / HOPSZ; if (t1 > TT - 1) t1 = TT - 1;
  int t0 = (j - (NFFT - HOPSZ)) / HOPSZ; if (t0 < 0) t0 = 0;
  const float* fb_ = frames + (size_t)b * TT * NFFT;
  float s = 0.f;
  for (int t = t0; t <= t1; ++t) s += fb_[t * NFFT + (j - t * HOPSZ)];
  y[idx] = s / wsqs[j];
}

// ---------------- epilogue: peak-normalize ----------------
__global__ void k_absmax(const float* __restrict__ y, float* __restrict__ peak) {
  __shared__ float red[256];
  int b = blockIdx.x;
  const float* yb = y + (size_t)b * LY + PADW;
  float mx = 0.f;
  for (int j = threadIdx.x; j < LOUTW; j += 256) mx = fmaxf(mx, fabsf(yb[j]));
  red[threadIdx.x] = mx;
  __syncthreads();
  for (int s2 = 128; s2 > 0; s2 >>= 1) {
    if (threadIdx.x < s2) red[threadIdx.x] = fmaxf(red[threadIdx.x], red[threadIdx.x + s2]);
    __syncthreads();
  }
  if (threadIdx.x == 0) peak[b] = red[0];
}

__global__ void k_scale(const float* __restrict__ y, const float* __restrict__ peak,
                        float* __restrict__ out, float target) {
  int idx = blockIdx.x * blockDim.x + threadIdx.x;
  if (idx >= NB * LOUTW) return;
  int b = idx / LOUTW, j = idx - b * LOUTW;
  out[idx] = y[(size_t)b * LY + PADW + j] * (target / peak[b]);
}

__global__ void k_zero2(float* __restrict__ a, float* __restrict__ b, int n) {
  int i = blockIdx.x * blockDim.x + threadIdx.x;
  if (i < n) { a[i] = 0.f; b[i] = 0.f; }
}

// ---------------- host ----------------
extern "C" void kernel_launch(void* const* d_in, const int* in_sizes, int n_in,
                              void* d_out, int out_size, void* d_ws, size_t ws_size,
                              hipStream_t stream) {
  const float* xmel = (const float*)d_in[0];   // (8, 80, 512) f32
  float* out = (float*)d_out;                  // (8, 1, 102200) f32

  char* p = (char*)d_ws;
  auto alloc = [&](size_t nbytes) -> void* {
    void* r = (void*)p;
    p += (nbytes + 255) & ~(size_t)255;
    return r;
  };
  float* mag  = (float*)alloc((size_t)NSPEC * 4);
  float* ar   = (float*)alloc((size_t)NSPEC * 4);
  float* ai   = (float*)alloc((size_t)NSPEC * 4);
  float* tpr  = (float*)alloc((size_t)NSPEC * 4);
  float* tpi  = (float*)alloc((size_t)NSPEC * 4);
  float* y    = (float*)alloc((size_t)NB * LY * 4);
  float* win  = (float*)alloc(NFFT * 4);
  float* wsqs = (float*)alloc((size_t)LY * 4);
  float* fbT  = (float*)alloc((size_t)NMELS * NFREQ * 4);
  float* fw0  = (float*)alloc(NFREQ * 4);
  float* fw1  = (float*)alloc(NFREQ * 4);
  float* peak = (float*)alloc(NB * 4);
  int* fm0    = (int*)alloc(NFREQ * 4);
  int* mlo    = (int*)alloc(NMELS * 4);
  int* mhi    = (int*)alloc(NMELS * 4);
  float* frames = (float*)alloc((size_t)NROWS * NFFT * 4);
  float* spec0 = frames;  // alias: consumed by k_sgd before frames written
  _Float16* A1h = (_Float16*)alloc((size_t)NROWS * K1P * 2);
  _Float16* A1l = (_Float16*)alloc((size_t)NROWS * K1P * 2);
  _Float16* A2h = (_Float16*)alloc((size_t)NROWS * K2 * 2);
  _Float16* A2l = (_Float16*)alloc((size_t)NROWS * K2 * 2);
  _Float16* B1h = (_Float16*)alloc((size_t)N1P * K1P * 2);
  _Float16* B1l = (_Float16*)alloc((size_t)N1P * K1P * 2);
  _Float16* B2ch = (_Float16*)alloc((size_t)N2P * K2 * 2);
  _Float16* B2cl = (_Float16*)alloc((size_t)N2P * K2 * 2);
  _Float16* B2sh = (_Float16*)alloc((size_t)N2P * K2 * 2);
  _Float16* B2sl = (_Float16*)alloc((size_t)N2P * K2 * 2);

  if ((size_t)(p - (char*)d_ws) > ws_size) return;  // insufficient scratch

  // derived threefry keys (jax partitionable split)
  unsigned k1a, k1b, k2a, k2b, kra, krb, kia, kib;
  {
    unsigned o0, o1;
    tf2x32(0u, 1u, 0u, 0u, o0, o1); k1a = o0; k1b = o1;
    tf2x32(0u, 1u, 0u, 1u, o0, o1); k2a = o0; k2b = o1;
    tf2x32(k2a, k2b, 0u, 0u, o0, o1); kra = o0; krb = o1;
    tf2x32(k2a, k2b, 0u, 1u, o0, o1); kia = o0; kib = o1;
  }

  // init
  k_fb<<<2, 256, 0, stream>>>(fbT, fm0, fw0, fw1);
  k_ranges<<<1, 128, 0, stream>>>(fbT, mlo, mhi);
  k_wsq<<<(LY + 255) / 256, 256, 0, stream>>>(wsqs, win);
  k_tabs1<<<(N1P * K1P + 255) / 256, 256, 0, stream>>>(B1h, B1l);
  k_tabs2<<<(N2P * K2 + 255) / 256, 256, 0, stream>>>(B2ch, B2cl, B2sh, B2sl);
  k_zero2<<<(NSPEC + 255) / 256, 256, 0, stream>>>(tpr, tpi, NSPEC);
  k_rand_spec<<<(NSPEC + 255) / 256, 256, 0, stream>>>(k1a, k1b, spec0);
  k_rand_ang<<<(NSPEC + 255) / 256, 256, 0, stream>>>(kra, krb, kia, kib, ar, ai);

  // InverseMelScale
  k_sgd<<<NROWS, 128, 0, stream>>>(spec0, xmel, fbT, mlo, mhi, fm0, fw0, fw1, mag);

  // iteration-0 A1 (also zero-fills the K pad [802,832) once; mm2 never touches it)
  k_prep1<<<dim3(4, NROWS), 256, 0, stream>>>(mag, ar, ai, A1h, A1l);

  // Griffin-Lim: 3 dispatches per iteration
  const float beta = (float)(0.99 / 1.99);
  for (int it = 0; it < GLITERS; ++it) {
    k_mm1<<<dim3(7, 128), 128, 0, stream>>>(A1h, A1l, B1h, B1l, frames);
    k_olaprep<<<(NROWS * K2 + 255) / 256, 256, 0, stream>>>(frames, wsqs, win, A2h, A2l);
    k_mm2<<<dim3(7, 128), 128, 0, stream>>>(A2h, A2l, B2ch, B2cl, B2sh, B2sl,
                                            mag, tpr, tpi, A1h, A1l, beta);
  }
  // final istft with final angles (A1 written by last k_mm2)
  k_mm1<<<dim3(7, 128), 128, 0, stream>>>(A1h, A1l, B1h, B1l, frames);
  k_ola<<<(NB * LY + 255) / 256, 256, 0, stream>>>(frames, wsqs, y);

  // normalize
  k_absmax<<<NB, 256, 0, stream>>>(y, peak);
  const float target = (float)pow(10.0, -0.1 / 20.0);
  k_scale<<<(NB * LOUTW + 255) / 256, 256, 0, stream>>>(y, peak, out, target);
}

// Round 7
// 3554.968 us; speedup vs baseline: 1.5154x; 1.5154x over previous
//
#include <hip/hip_runtime.h>
#include <math.h>

// ---------------- problem constants ----------------
#define NB 8
#define NMELS 80
#define TT 512
#define NFREQ 401
#define NFFT 800
#define HOPSZ 200
#define NROWS (NB*TT)          // 4096 frames
#define LY 103000              // untrimmed istft length
#define LOUTW 102200
#define PADW 400
#define NSPEC (NROWS*NFREQ)    // 1640448
#define GLITERS 30
#define SGDITERS 50
#define SGD_SCALE 0.003125f    // 2/(B*n_mels)
#define K1P 832                // irfft GEMM K padded (26*32)
#define K2 800                 // rfft GEMM K (25*32)
#define N1P 896                // irfft GEMM N padded (14*64)
#define N2P 512                // rfft GEMM N padded (8*64)
// scales: A x256, B1 x(800*16) [/800 dropped + 16], lo parts x2048
#define WSQ_SCALE 3276800.0f   // 800*16*256
#define LO_INV 4.8828125e-4f   // 2^-11

#define TWO_PI_D 6.283185307179586476925286766559

typedef _Float16 half8 __attribute__((ext_vector_type(8)));
typedef float f32x4 __attribute__((ext_vector_type(4)));

// ---------------- threefry2x32 (20 rounds) ----------------
__host__ __device__ inline void tf2x32(unsigned k0, unsigned k1,
                                       unsigned x0, unsigned x1,
                                       unsigned& o0, unsigned& o1) {
  unsigned ks0 = k0, ks1 = k1, ks2 = k0 ^ k1 ^ 0x1BD11BDAu;
  x0 += ks0; x1 += ks1;
#define TF_R(r) { x0 += x1; x1 = (x1 << (r)) | (x1 >> (32 - (r))); x1 ^= x0; }
  TF_R(13) TF_R(15) TF_R(26) TF_R(6)
  x0 += ks1; x1 += ks2 + 1u;
  TF_R(17) TF_R(29) TF_R(16) TF_R(24)
  x0 += ks2; x1 += ks0 + 2u;
  TF_R(13) TF_R(15) TF_R(26) TF_R(6)
  x0 += ks0; x1 += ks1 + 3u;
  TF_R(17) TF_R(29) TF_R(16) TF_R(24)
  x0 += ks1; x1 += ks2 + 4u;
  TF_R(13) TF_R(15) TF_R(26) TF_R(6)
  x0 += ks2; x1 += ks0 + 5u;
#undef TF_R
  o0 = x0; o1 = x1;
}

__device__ inline float u01(unsigned bits) {
  unsigned u = (bits >> 9) | 0x3f800000u;
  return __uint_as_float(u) - 1.0f;
}

__device__ inline int ang_map(int g) {
  int b = g / (NFREQ * TT);
  int r = g - b * (NFREQ * TT);
  int f = r / TT;
  int t = r - f * TT;
  return (b * TT + t) * NFREQ + f;
}

__global__ void k_rand_spec(unsigned ka, unsigned kb, float* __restrict__ spec) {
  int i = blockIdx.x * blockDim.x + threadIdx.x;
  if (i >= NSPEC) return;
  unsigned o0, o1; tf2x32(ka, kb, 0u, (unsigned)i, o0, o1);
  spec[i] = u01(o0 ^ o1);    // partitionable 32-bit fold
}

__global__ void k_rand_ang(unsigned kra, unsigned krb, unsigned kia, unsigned kib,
                           float* __restrict__ ar, float* __restrict__ ai) {
  int g = blockIdx.x * blockDim.x + threadIdx.x;
  if (g >= NSPEC) return;
  int d = ang_map(g);
  unsigned o0, o1;
  tf2x32(kra, krb, 0u, (unsigned)g, o0, o1); ar[d] = u01(o0 ^ o1);
  tf2x32(kia, kib, 0u, (unsigned)g, o0, o1); ai[d] = u01(o0 ^ o1);
}

// ---------------- mel filterbank ----------------
__device__ inline double mel2hz_d(double mel) {
  return 700.0 * (pow(10.0, mel / 2595.0) - 1.0);
}

__global__ void k_fb(float* __restrict__ fbT, int* __restrict__ fm0,
                     float* __restrict__ fw0, float* __restrict__ fw1) {
  int f = blockIdx.x * blockDim.x + threadIdx.x;
  if (f >= NFREQ) return;
  const double freq = 10.0 * (double)f;
  const double melmax = 2595.0 * log10(1.0 + 4000.0 / 700.0);
  const double step = melmax / 81.0;
  int first = -1; float w0v = 0.f, w1v = 0.f;
  double p0 = 0.0;
  double p1 = mel2hz_d(step);
  for (int m = 0; m < NMELS; ++m) {
    double m2 = (m + 2 == 81) ? melmax : (double)(m + 2) * step;
    double p2 = mel2hz_d(m2);
    double down = (freq - p0) / (p1 - p0);
    double up   = (p2 - freq) / (p2 - p1);
    double v = down < up ? down : up;
    if (v < 0.0) v = 0.0;
    float vf = (float)v;
    fbT[m * NFREQ + f] = vf;
    if (vf > 0.f) {
      if (first < 0) { first = m; w0v = vf; }
      else if (m == first + 1) { w1v = vf; }
    }
    p0 = p1; p1 = p2;
  }
  fm0[f] = first < 0 ? 0 : first;
  fw0[f] = first < 0 ? 0.f : w0v;
  fw1[f] = w1v;
}

__global__ void k_ranges(const float* __restrict__ fbT, int* __restrict__ mlo,
                         int* __restrict__ mhi) {
  int m = threadIdx.x;
  if (m >= NMELS) return;
  int lo = NFREQ, hi = 0;
  for (int f = 0; f < NFREQ; ++f)
    if (fbT[m * NFREQ + f] > 0.f) { if (lo == NFREQ) lo = f; hi = f + 1; }
  mlo[m] = lo; mhi[m] = hi < lo ? lo : hi;
}

// ---------------- window + OLA weight (pre-scaled) ----------------
__device__ inline double hann_d(int i) {
  return 0.5 - 0.5 * cos(TWO_PI_D * (double)i / 800.0);
}

__global__ void k_wsq(float* __restrict__ wsqs, float* __restrict__ win) {
  int j = blockIdx.x * blockDim.x + threadIdx.x;
  if (j >= LY) return;
  if (j < NFFT) win[j] = (float)hann_d(j);
  int t1 = j / HOPSZ; if (t1 > TT - 1) t1 = TT - 1;
  int t0 = (j - (NFFT - HOPSZ)) / HOPSZ; if (t0 < 0) t0 = 0;
  float s = 0.f;
  for (int t = t0; t <= t1; ++t) {
    float w = (float)hann_d(j - t * HOPSZ);
    s += w * w;
  }
  wsqs[j] = WSQ_SCALE * fmaxf(s, 1e-11f);
}

// ---------------- f16-split DFT tables ----------------
// B1 (irfft, transposed [n=time][kk=freq-row]), scaled x16, /800 dropped
__global__ void k_tabs1(_Float16* __restrict__ Bh, _Float16* __restrict__ Bl) {
  int idx = blockIdx.x * blockDim.x + threadIdx.x;
  if (idx >= N1P * K1P) return;
  int n = idx / K1P, kk = idx - n * K1P;
  double v = 0.0;
  if (n < NFFT && kk < 802) {
    double wn = hann_d(n);
    if (kk < NFREQ) {
      int k = kk;
      double ak = (k == 0 || k == 400) ? 1.0 : 2.0;
      int ph = (k * n) % NFFT;
      v = 16.0 * ak * cos((double)ph * (TWO_PI_D / 800.0)) * wn;
    } else {
      int k = kk - NFREQ;
      if (k != 0 && k != 400) {
        int ph = (k * n) % NFFT;
        v = 16.0 * (-2.0) * sin((double)ph * (TWO_PI_D / 800.0)) * wn;
      }
    }
  }
  float vf = (float)v;
  _Float16 h = (_Float16)vf;
  Bh[idx] = h;
  Bl[idx] = (_Float16)((vf - (float)h) * 2048.0f);
}

// B2 (rfft, transposed [n=freq-col][k=time]): cos and -sin
__global__ void k_tabs2(_Float16* __restrict__ Bch, _Float16* __restrict__ Bcl,
                        _Float16* __restrict__ Bsh, _Float16* __restrict__ Bsl) {
  int idx = blockIdx.x * blockDim.x + threadIdx.x;
  if (idx >= N2P * K2) return;
  int n = idx / K2, k = idx - n * K2;
  double c = 0.0, s = 0.0;
  if (n < NFREQ) {
    int ph = (n * k) % NFFT;
    double ang = (double)ph * (TWO_PI_D / 800.0);
    c = cos(ang); s = -sin(ang);
  }
  float cf = (float)c, sf = (float)s;
  _Float16 ch = (_Float16)cf, sh = (_Float16)sf;
  Bch[idx] = ch; Bcl[idx] = (_Float16)((cf - (float)ch) * 2048.0f);
  Bsh[idx] = sh; Bsl[idx] = (_Float16)((sf - (float)sh) * 2048.0f);
}

// ---------------- InverseMelScale: 50 SGD iterations, 1 wave per row ----------------
__global__ __launch_bounds__(64) void k_sgd(
    const float* __restrict__ spec0, const float* __restrict__ xmel,
    const float* __restrict__ fbT, const int* __restrict__ mlo,
    const int* __restrict__ mhi, const int* __restrict__ fm0,
    const float* __restrict__ fw0, const float* __restrict__ fw1,
    float* __restrict__ mag) {
  __shared__ float s_spec[NFREQ], s_vel[NFREQ], s_diff[NMELS], s_mel[NMELS];
  const int row = blockIdx.x;
  const int b = row / TT, t = row - b * TT;
  const int tid = threadIdx.x;
  for (int f = tid; f < NFREQ; f += 64) { s_spec[f] = spec0[row * NFREQ + f]; s_vel[f] = 0.f; }
  for (int m = tid; m < NMELS; m += 64) s_mel[m] = xmel[(b * NMELS + m) * TT + t];
  __syncthreads();
  for (int it = 0; it < SGDITERS; ++it) {
    for (int m = tid; m < NMELS; m += 64) {
      float acc = 0.f;
      const int lo = mlo[m], hi = mhi[m];
      const float* fr = fbT + m * NFREQ;
      for (int f = lo; f < hi; ++f) acc = fmaf(s_spec[f], fr[f], acc);
      s_diff[m] = s_mel[m] - acc;
    }
    __syncthreads();
    for (int f = tid; f < NFREQ; f += 64) {
      int m0 = fm0[f];
      int m1 = m0 + 1; if (m1 > NMELS - 1) m1 = NMELS - 1;
      float d = s_diff[m0] * fw0[f] + s_diff[m1] * fw1[f];
      float g = -SGD_SCALE * d;
      float v = 0.9f * s_vel[f] + g;
      s_vel[f] = v;
      float sp = s_spec[f] - 0.1f * v;
      s_spec[f] = sp > 0.f ? sp : 0.f;
    }
    __syncthreads();
  }
  for (int f = tid; f < NFREQ; f += 64) mag[row * NFREQ + f] = sqrtf(s_spec[f]);
}

// ---------------- A1 prep (iteration 0 only; zero-fills K pad once) ----------------
__global__ void k_prep1(const float* __restrict__ mag, const float* __restrict__ ar,
                        const float* __restrict__ ai,
                        _Float16* __restrict__ Ah, _Float16* __restrict__ Al) {
  int kk = blockIdx.x * 256 + threadIdx.x;
  if (kk >= K1P) return;
  int row = blockIdx.y;
  float v = 0.f;
  if (kk < 802) {
    int k = (kk < NFREQ) ? kk : kk - NFREQ;
    int gi = row * NFREQ + k;
    float aa = (kk < NFREQ) ? ar[gi] : ai[gi];
    v = mag[gi] * aa * 256.0f;
  }
  _Float16 h = (_Float16)v;
  size_t o = (size_t)row * K1P + kk;
  Ah[o] = h;
  Al[o] = (_Float16)((v - (float)h) * 2048.0f);
}

// ---------------- MFMA split-f16 GEMM 1: frames = A1 @ B1 ----------------
// 64(M) x 64(N) tile, 4 waves in 2x2, each 32x32; grid (14, 64) = 896 blocks
__global__ __launch_bounds__(256, 2) void k_mm1(
    const _Float16* __restrict__ Ah, const _Float16* __restrict__ Al,
    const _Float16* __restrict__ Bh, const _Float16* __restrict__ Bl,
    float* __restrict__ frames) {
  __shared__ __align__(16) _Float16 As_h[64 * 40], As_l[64 * 40];
  __shared__ __align__(16) _Float16 Bs_h[64 * 40], Bs_l[64 * 40];
  const int t = threadIdx.x;
  const int row0 = blockIdx.y * 64;
  const int col0 = blockIdx.x * 64;
  const int sr_ = t >> 2, sk_ = (t & 3) * 8;   // staging: 1 uint4 per buffer
  const int lane = t & 63, wv = t >> 6;
  const int wm = wv & 1, wn = wv >> 1;
  const int lm = lane & 15, qd = lane >> 4;
  f32x4 acc0[2][2] = {}, acc1[2][2] = {};
  const size_t abase = (size_t)(row0 + sr_) * K1P;
  const size_t bbase = (size_t)(col0 + sr_) * K1P;
  for (int k0 = 0; k0 < K1P; k0 += 32) {
    *(uint4*)&As_h[sr_ * 40 + sk_] = *(const uint4*)&Ah[abase + k0 + sk_];
    *(uint4*)&As_l[sr_ * 40 + sk_] = *(const uint4*)&Al[abase + k0 + sk_];
    *(uint4*)&Bs_h[sr_ * 40 + sk_] = *(const uint4*)&Bh[bbase + k0 + sk_];
    *(uint4*)&Bs_l[sr_ * 40 + sk_] = *(const uint4*)&Bl[bbase + k0 + sk_];
    __syncthreads();
    half8 a_h[2], a_l[2];
#pragma unroll
    for (int i = 0; i < 2; ++i) {
      int m = wm * 32 + i * 16 + lm;
      a_h[i] = *(const half8*)&As_h[m * 40 + qd * 8];
      a_l[i] = *(const half8*)&As_l[m * 40 + qd * 8];
    }
#pragma unroll
    for (int j = 0; j < 2; ++j) {
      int n = wn * 32 + j * 16 + lm;
      half8 b_h = *(const half8*)&Bs_h[n * 40 + qd * 8];
      half8 b_l = *(const half8*)&Bs_l[n * 40 + qd * 8];
#pragma unroll
      for (int i = 0; i < 2; ++i) {
        acc0[i][j] = __builtin_amdgcn_mfma_f32_16x16x32_f16(a_h[i], b_h, acc0[i][j], 0, 0, 0);
        acc1[i][j] = __builtin_amdgcn_mfma_f32_16x16x32_f16(a_h[i], b_l, acc1[i][j], 0, 0, 0);
        acc1[i][j] = __builtin_amdgcn_mfma_f32_16x16x32_f16(a_l[i], b_h, acc1[i][j], 0, 0, 0);
      }
    }
    __syncthreads();
  }
#pragma unroll
  for (int j = 0; j < 2; ++j) {
    int col = col0 + wn * 32 + j * 16 + lm;
    if (col < NFFT) {
#pragma unroll
      for (int i = 0; i < 2; ++i)
#pragma unroll
        for (int r = 0; r < 4; ++r) {
          int row = row0 + wm * 32 + i * 16 + qd * 4 + r;
          frames[(size_t)row * NFFT + col] = acc0[i][j][r] + acc1[i][j][r] * LO_INV;
        }
    }
  }
}

// ---------------- overlap-add + /wsq : y(8x103000) ----------------
__global__ void k_ola(const float* __restrict__ frames, const float* __restrict__ wsqs,
                      float* __restrict__ y) {
  int idx = blockIdx.x * blockDim.x + threadIdx.x;
  if (idx >= NB * LY) return;
  int b = idx / LY, j = idx - b * LY;
  int t1 = j / HOPSZ; if (t1 > TT - 1) t1 = TT - 1;
  int t0 = (j - (NFFT - HOPSZ)) / HOPSZ; if (t0 < 0) t0 = 0;
  const float* fb_ = frames + (size_t)b * TT * NFFT;
  float s = 0.f;
  for (int t = t0; t <= t1; ++t) s += fb_[t * NFFT + (j - t * HOPSZ)];
  y[idx] = s / wsqs[j];
}

// ---------------- A2 prep (windowed frame, x256, vectorized 4/thread) ----------------
__global__ void k_prep2(const float* __restrict__ y, const float* __restrict__ win,
                        _Float16* __restrict__ Ah, _Float16* __restrict__ Al) {
  int e4 = blockIdx.x * 256 + threadIdx.x;          // element group of 4
  if (e4 >= NROWS * K2 / 4) return;
  int e0 = e4 * 4;
  int row = e0 / K2, k0 = e0 - row * K2;            // 800%4==0 -> same row
  int b = row >> 9, tt = row & 511;
  const float* yb = y + (size_t)b * LY;
  _Float16 hs[4], ls[4];
#pragma unroll
  for (int q = 0; q < 4; ++q) {
    int k = k0 + q;
    int j = tt * HOPSZ + k;
    int jm = (j < PADW) ? (NFFT - j) : ((j < PADW + LOUTW) ? j : (205198 - j));
    float v = yb[jm] * win[k] * 256.0f;
    _Float16 h = (_Float16)v;
    hs[q] = h;
    ls[q] = (_Float16)((v - (float)h) * 2048.0f);
  }
  *(ushort4*)&Ah[e0] = *(ushort4*)hs;
  *(ushort4*)&Al[e0] = *(ushort4*)ls;
}

// ---------------- MFMA split-f16 GEMM 2: rfft + momentum + normalize + A1' ----------------
// 64(M) x 64(N) tile, 4 waves 2x2; grid (8, 64) = 512 blocks
__global__ __launch_bounds__(256, 2) void k_mm2(
    const _Float16* __restrict__ Ah, const _Float16* __restrict__ Al,
    const _Float16* __restrict__ Bch, const _Float16* __restrict__ Bcl,
    const _Float16* __restrict__ Bsh, const _Float16* __restrict__ Bsl,
    const float* __restrict__ mag,
    float* __restrict__ tppr, float* __restrict__ tppi,
    _Float16* __restrict__ A1h, _Float16* __restrict__ A1l, float beta) {
  __shared__ __align__(16) _Float16 As_h[64 * 40], As_l[64 * 40];
  __shared__ __align__(16) _Float16 Bc_h[64 * 40], Bc_l[64 * 40];
  __shared__ __align__(16) _Float16 Bn_h[64 * 40], Bn_l[64 * 40];
  const int t = threadIdx.x;
  const int row0 = blockIdx.y * 64;
  const int col0 = blockIdx.x * 64;
  const int sr_ = t >> 2, sk_ = (t & 3) * 8;
  const int lane = t & 63, wv = t >> 6;
  const int wm = wv & 1, wn = wv >> 1;
  const int lm = lane & 15, qd = lane >> 4;
  f32x4 cr0[2][2] = {}, cr1[2][2] = {}, ci0[2][2] = {}, ci1[2][2] = {};
  const size_t abase = (size_t)(row0 + sr_) * K2;
  const size_t bbase = (size_t)(col0 + sr_) * K2;
  for (int k0 = 0; k0 < K2; k0 += 32) {
    *(uint4*)&As_h[sr_ * 40 + sk_] = *(const uint4*)&Ah[abase + k0 + sk_];
    *(uint4*)&As_l[sr_ * 40 + sk_] = *(const uint4*)&Al[abase + k0 + sk_];
    *(uint4*)&Bc_h[sr_ * 40 + sk_] = *(const uint4*)&Bch[bbase + k0 + sk_];
    *(uint4*)&Bc_l[sr_ * 40 + sk_] = *(const uint4*)&Bcl[bbase + k0 + sk_];
    *(uint4*)&Bn_h[sr_ * 40 + sk_] = *(const uint4*)&Bsh[bbase + k0 + sk_];
    *(uint4*)&Bn_l[sr_ * 40 + sk_] = *(const uint4*)&Bsl[bbase + k0 + sk_];
    __syncthreads();
    half8 a_h[2], a_l[2];
#pragma unroll
    for (int i = 0; i < 2; ++i) {
      int m = wm * 32 + i * 16 + lm;
      a_h[i] = *(const half8*)&As_h[m * 40 + qd * 8];
      a_l[i] = *(const half8*)&As_l[m * 40 + qd * 8];
    }
#pragma unroll
    for (int j = 0; j < 2; ++j) {
      int n = wn * 32 + j * 16 + lm;
      half8 bc_h = *(const half8*)&Bc_h[n * 40 + qd * 8];
      half8 bc_l = *(const half8*)&Bc_l[n * 40 + qd * 8];
      half8 bs_h = *(const half8*)&Bn_h[n * 40 + qd * 8];
      half8 bs_l = *(const half8*)&Bn_l[n * 40 + qd * 8];
#pragma unroll
      for (int i = 0; i < 2; ++i) {
        cr0[i][j] = __builtin_amdgcn_mfma_f32_16x16x32_f16(a_h[i], bc_h, cr0[i][j], 0, 0, 0);
        cr1[i][j] = __builtin_amdgcn_mfma_f32_16x16x32_f16(a_h[i], bc_l, cr1[i][j], 0, 0, 0);
        cr1[i][j] = __builtin_amdgcn_mfma_f32_16x16x32_f16(a_l[i], bc_h, cr1[i][j], 0, 0, 0);
        ci0[i][j] = __builtin_amdgcn_mfma_f32_16x16x32_f16(a_h[i], bs_h, ci0[i][j], 0, 0, 0);
        ci1[i][j] = __builtin_amdgcn_mfma_f32_16x16x32_f16(a_h[i], bs_l, ci1[i][j], 0, 0, 0);
        ci1[i][j] = __builtin_amdgcn_mfma_f32_16x16x32_f16(a_l[i], bs_h, ci1[i][j], 0, 0, 0);
      }
    }
    __syncthreads();
  }
#pragma unroll
  for (int j = 0; j < 2; ++j) {
    int col = col0 + wn * 32 + j * 16 + lm;
    if (col < NFREQ) {
#pragma unroll
      for (int i = 0; i < 2; ++i)
#pragma unroll
        for (int r = 0; r < 4; ++r) {
          int row = row0 + wm * 32 + i * 16 + qd * 4 + r;
          int idx = row * NFREQ + col;
          float rr = cr0[i][j][r] + cr1[i][j][r] * LO_INV;   // (x256-scaled rebuilt)
          float ri = ci0[i][j][r] + ci1[i][j][r] * LO_INV;
          float nr = rr - beta * tppr[idx];
          float ni = ri - beta * tppi[idx];
          tppr[idx] = rr; tppi[idx] = ri;
          float den = sqrtf(nr * nr + ni * ni) + 1e-16f;
          float arv = nr / den, aiv = ni / den;
          // fused next-iteration A1 = mag * ang * 256 (split f16)
          float mg = mag[idx] * 256.0f;
          size_t ab = (size_t)row * K1P;
          float v1 = mg * arv;
          _Float16 h1 = (_Float16)v1;
          A1h[ab + col] = h1;
          A1l[ab + col] = (_Float16)((v1 - (float)h1) * 2048.0f);
          float v2 = mg * aiv;
          _Float16 h2 = (_Float16)v2;
          A1h[ab + NFREQ + col] = h2;
          A1l[ab + NFREQ + col] = (_Float16)((v2 - (float)h2) * 2048.0f);
        }
    }
  }
}

// ---------------- epilogue: peak-normalize ----------------
__global__ void k_absmax(const float* __restrict__ y, float* __restrict__ peak) {
  __shared__ float red[256];
  int b = blockIdx.x;
  const float* yb = y + (size_t)b * LY + PADW;
  float mx = 0.f;
  for (int j = threadIdx.x; j < LOUTW; j += 256) mx = fmaxf(mx, fabsf(yb[j]));
  red[threadIdx.x] = mx;
  __syncthreads();
  for (int s2 = 128; s2 > 0; s2 >>= 1) {
    if (threadIdx.x < s2) red[threadIdx.x] = fmaxf(red[threadIdx.x], red[threadIdx.x + s2]);
    __syncthreads();
  }
  if (threadIdx.x == 0) peak[b] = red[0];
}

__global__ void k_scale(const float* __restrict__ y, const float* __restrict__ peak,
                        float* __restrict__ out, float target) {
  int idx = blockIdx.x * blockDim.x + threadIdx.x;
  if (idx >= NB * LOUTW) return;
  int b = idx / LOUTW, j = idx - b * LOUTW;
  out[idx] = y[(size_t)b * LY + PADW + j] * (target / peak[b]);
}

__global__ void k_zero2(float* __restrict__ a, float* __restrict__ b, int n) {
  int i = blockIdx.x * blockDim.x + threadIdx.x;
  if (i < n) { a[i] = 0.f; b[i] = 0.f; }
}

// ---------------- host ----------------
extern "C" void kernel_launch(void* const* d_in, const int* in_sizes, int n_in,
                              void* d_out, int out_size, void* d_ws, size_t ws_size,
                              hipStream_t stream) {
  const float* xmel = (const float*)d_in[0];   // (8, 80, 512) f32
  float* out = (float*)d_out;                  // (8, 1, 102200) f32

  char* p = (char*)d_ws;
  auto alloc = [&](size_t nbytes) -> void* {
    void* r = (void*)p;
    p += (nbytes + 255) & ~(size_t)255;
    return r;
  };
  float* mag  = (float*)alloc((size_t)NSPEC * 4);
  float* ar   = (float*)alloc((size_t)NSPEC * 4);
  float* ai   = (float*)alloc((size_t)NSPEC * 4);
  float* tpr  = (float*)alloc((size_t)NSPEC * 4);
  float* tpi  = (float*)alloc((size_t)NSPEC * 4);
  float* y    = (float*)alloc((size_t)NB * LY * 4);
  float* win  = (float*)alloc(NFFT * 4);
  float* wsqs = (float*)alloc((size_t)LY * 4);
  float* fbT  = (float*)alloc((size_t)NMELS * NFREQ * 4);
  float* fw0  = (float*)alloc(NFREQ * 4);
  float* fw1  = (float*)alloc(NFREQ * 4);
  float* peak = (float*)alloc(NB * 4);
  int* fm0    = (int*)alloc(NFREQ * 4);
  int* mlo    = (int*)alloc(NMELS * 4);
  int* mhi    = (int*)alloc(NMELS * 4);
  float* frames = (float*)alloc((size_t)NROWS * NFFT * 4);
  float* spec0 = frames;  // alias: consumed by k_sgd before frames written
  _Float16* A1h = (_Float16*)alloc((size_t)NROWS * K1P * 2);
  _Float16* A1l = (_Float16*)alloc((size_t)NROWS * K1P * 2);
  _Float16* A2h = (_Float16*)alloc((size_t)NROWS * K2 * 2);
  _Float16* A2l = (_Float16*)alloc((size_t)NROWS * K2 * 2);
  _Float16* B1h = (_Float16*)alloc((size_t)N1P * K1P * 2);
  _Float16* B1l = (_Float16*)alloc((size_t)N1P * K1P * 2);
  _Float16* B2ch = (_Float16*)alloc((size_t)N2P * K2 * 2);
  _Float16* B2cl = (_Float16*)alloc((size_t)N2P * K2 * 2);
  _Float16* B2sh = (_Float16*)alloc((size_t)N2P * K2 * 2);
  _Float16* B2sl = (_Float16*)alloc((size_t)N2P * K2 * 2);

  if ((size_t)(p - (char*)d_ws) > ws_size) return;  // insufficient scratch

  // derived threefry keys (jax partitionable split)
  unsigned k1a, k1b, k2a, k2b, kra, krb, kia, kib;
  {
    unsigned o0, o1;
    tf2x32(0u, 1u, 0u, 0u, o0, o1); k1a = o0; k1b = o1;
    tf2x32(0u, 1u, 0u, 1u, o0, o1); k2a = o0; k2b = o1;
    tf2x32(k2a, k2b, 0u, 0u, o0, o1); kra = o0; krb = o1;
    tf2x32(k2a, k2b, 0u, 1u, o0, o1); kia = o0; kib = o1;
  }

  // init
  k_fb<<<2, 256, 0, stream>>>(fbT, fm0, fw0, fw1);
  k_ranges<<<1, 128, 0, stream>>>(fbT, mlo, mhi);
  k_wsq<<<(LY + 255) / 256, 256, 0, stream>>>(wsqs, win);
  k_tabs1<<<(N1P * K1P + 255) / 256, 256, 0, stream>>>(B1h, B1l);
  k_tabs2<<<(N2P * K2 + 255) / 256, 256, 0, stream>>>(B2ch, B2cl, B2sh, B2sl);
  k_zero2<<<(NSPEC + 255) / 256, 256, 0, stream>>>(tpr, tpi, NSPEC);
  k_rand_spec<<<(NSPEC + 255) / 256, 256, 0, stream>>>(k1a, k1b, spec0);
  k_rand_ang<<<(NSPEC + 255) / 256, 256, 0, stream>>>(kra, krb, kia, kib, ar, ai);

  // InverseMelScale (1 wave per (b,t) row)
  k_sgd<<<NROWS, 64, 0, stream>>>(spec0, xmel, fbT, mlo, mhi, fm0, fw0, fw1, mag);

  // iteration-0 A1 (also zero-fills the K pad [802,832); mm2 never touches pad)
  k_prep1<<<dim3(4, NROWS), 256, 0, stream>>>(mag, ar, ai, A1h, A1l);

  // Griffin-Lim: 4 dispatches per iteration
  const float beta = (float)(0.99 / 1.99);
  for (int it = 0; it < GLITERS; ++it) {
    k_mm1<<<dim3(14, 64), 256, 0, stream>>>(A1h, A1l, B1h, B1l, frames);
    k_ola<<<(NB * LY + 255) / 256, 256, 0, stream>>>(frames, wsqs, y);
    k_prep2<<<(NROWS * K2 / 4 + 255) / 256, 256, 0, stream>>>(y, win, A2h, A2l);
    k_mm2<<<dim3(8, 64), 256, 0, stream>>>(A2h, A2l, B2ch, B2cl, B2sh, B2sl,
                                           mag, tpr, tpi, A1h, A1l, beta);
  }
  // final istft with final angles (A1 written by last k_mm2)
  k_mm1<<<dim3(14, 64), 256, 0, stream>>>(A1h, A1l, B1h, B1l, frames);
  k_ola<<<(NB * LY + 255) / 256, 256, 0, stream>>>(frames, wsqs, y);

  // normalize
  k_absmax<<<NB, 256, 0, stream>>>(y, peak);
  const float target = (float)pow(10.0, -0.1 / 20.0);
  k_scale<<<(NB * LOUTW + 255) / 256, 256, 0, stream>>>(y, peak, out, target);
}

// Round 9
// 2712.513 us; speedup vs baseline: 1.9861x; 1.3106x over previous
//
#include <hip/hip_runtime.h>
#include <math.h>

// ---------------- problem constants ----------------
#define NB 8
#define NMELS 80
#define TT 512
#define NFREQ 401
#define NFFT 800
#define HOPSZ 200
#define NROWS (NB*TT)          // 4096 frames
#define LY 103000              // untrimmed istft length
#define LOUTW 102200
#define PADW 400
#define NSPEC (NROWS*NFREQ)    // 1640448
#define GLITERS 30
#define SGDITERS 50
#define SGD_SCALE 0.003125f    // 2/(B*n_mels)
#define KCAT 832               // concatenated K: [part0 416 | part1 416]
#define KHALF 416
#define NCOLS 448              // padded output cols (7*64), valid [0,400]
// scales: A x256, B1 x16 (/800 dropped), lo parts x2048
#define WSQ_SCALE 3276800.0f   // 800*16*256
#define LO_INV 4.8828125e-4f   // 2^-11

#define TWO_PI_D 6.283185307179586476925286766559

typedef _Float16 half8 __attribute__((ext_vector_type(8)));
typedef float f32x4 __attribute__((ext_vector_type(4)));

// ---------------- threefry2x32 (20 rounds) ----------------
__host__ __device__ inline void tf2x32(unsigned k0, unsigned k1,
                                       unsigned x0, unsigned x1,
                                       unsigned& o0, unsigned& o1) {
  unsigned ks0 = k0, ks1 = k1, ks2 = k0 ^ k1 ^ 0x1BD11BDAu;
  x0 += ks0; x1 += ks1;
#define TF_R(r) { x0 += x1; x1 = (x1 << (r)) | (x1 >> (32 - (r))); x1 ^= x0; }
  TF_R(13) TF_R(15) TF_R(26) TF_R(6)
  x0 += ks1; x1 += ks2 + 1u;
  TF_R(17) TF_R(29) TF_R(16) TF_R(24)
  x0 += ks2; x1 += ks0 + 2u;
  TF_R(13) TF_R(15) TF_R(26) TF_R(6)
  x0 += ks0; x1 += ks1 + 3u;
  TF_R(17) TF_R(29) TF_R(16) TF_R(24)
  x0 += ks1; x1 += ks2 + 4u;
  TF_R(13) TF_R(15) TF_R(26) TF_R(6)
  x0 += ks2; x1 += ks0 + 5u;
#undef TF_R
  o0 = x0; o1 = x1;
}

__device__ inline float u01(unsigned bits) {
  unsigned u = (bits >> 9) | 0x3f800000u;
  return __uint_as_float(u) - 1.0f;
}

__device__ inline int ang_map(int g) {
  int b = g / (NFREQ * TT);
  int r = g - b * (NFREQ * TT);
  int f = r / TT;
  int t = r - f * TT;
  return (b * TT + t) * NFREQ + f;
}

__global__ void k_rand_spec(unsigned ka, unsigned kb, float* __restrict__ spec) {
  int i = blockIdx.x * blockDim.x + threadIdx.x;
  if (i >= NSPEC) return;
  unsigned o0, o1; tf2x32(ka, kb, 0u, (unsigned)i, o0, o1);
  spec[i] = u01(o0 ^ o1);    // partitionable 32-bit fold
}

__global__ void k_rand_ang(unsigned kra, unsigned krb, unsigned kia, unsigned kib,
                           float* __restrict__ ar, float* __restrict__ ai) {
  int g = blockIdx.x * blockDim.x + threadIdx.x;
  if (g >= NSPEC) return;
  int d = ang_map(g);
  unsigned o0, o1;
  tf2x32(kra, krb, 0u, (unsigned)g, o0, o1); ar[d] = u01(o0 ^ o1);
  tf2x32(kia, kib, 0u, (unsigned)g, o0, o1); ai[d] = u01(o0 ^ o1);
}

// ---------------- mel filterbank ----------------
__device__ inline double mel2hz_d(double mel) {
  return 700.0 * (pow(10.0, mel / 2595.0) - 1.0);
}

__global__ void k_fb(float* __restrict__ fbT, int* __restrict__ fm0,
                     float* __restrict__ fw0, float* __restrict__ fw1) {
  int f = blockIdx.x * blockDim.x + threadIdx.x;
  if (f >= NFREQ) return;
  const double freq = 10.0 * (double)f;
  const double melmax = 2595.0 * log10(1.0 + 4000.0 / 700.0);
  const double step = melmax / 81.0;
  int first = -1; float w0v = 0.f, w1v = 0.f;
  double p0 = 0.0;
  double p1 = mel2hz_d(step);
  for (int m = 0; m < NMELS; ++m) {
    double m2 = (m + 2 == 81) ? melmax : (double)(m + 2) * step;
    double p2 = mel2hz_d(m2);
    double down = (freq - p0) / (p1 - p0);
    double up   = (p2 - freq) / (p2 - p1);
    double v = down < up ? down : up;
    if (v < 0.0) v = 0.0;
    float vf = (float)v;
    fbT[m * NFREQ + f] = vf;
    if (vf > 0.f) {
      if (first < 0) { first = m; w0v = vf; }
      else if (m == first + 1) { w1v = vf; }
    }
    p0 = p1; p1 = p2;
  }
  fm0[f] = first < 0 ? 0 : first;
  fw0[f] = first < 0 ? 0.f : w0v;
  fw1[f] = w1v;
}

__global__ void k_ranges(const float* __restrict__ fbT, int* __restrict__ mlo,
                         int* __restrict__ mhi) {
  int m = threadIdx.x;
  if (m >= NMELS) return;
  int lo = NFREQ, hi = 0;
  for (int f = 0; f < NFREQ; ++f)
    if (fbT[m * NFREQ + f] > 0.f) { if (lo == NFREQ) lo = f; hi = f + 1; }
  mlo[m] = lo; mhi[m] = hi < lo ? lo : hi;
}

// ---------------- window + OLA weight (pre-scaled) ----------------
__device__ inline double hann_d(int i) {
  return 0.5 - 0.5 * cos(TWO_PI_D * (double)i / 800.0);
}

__global__ void k_wsq(float* __restrict__ wsqs, float* __restrict__ win) {
  int j = blockIdx.x * blockDim.x + threadIdx.x;
  if (j >= LY) return;
  if (j < NFFT) win[j] = (float)hann_d(j);
  int t1 = j / HOPSZ; if (t1 > TT - 1) t1 = TT - 1;
  int t0 = (j - (NFFT - HOPSZ)) / HOPSZ; if (t0 < 0) t0 = 0;
  float s = 0.f;
  for (int t = t0; t <= t1; ++t) {
    float w = (float)hann_d(j - t * HOPSZ);
    s += w * w;
  }
  wsqs[j] = WSQ_SCALE * fmaxf(s, 1e-11f);
}

// ---------------- symmetric f16-split DFT tables ----------------
// B1 [n=time col 0..447][kk 0..831]: kk<416: 16*ak*cos(2pi k n/800) (k=kk)
//                                    kk>=416: -32*sin(2pi k n/800) (k=kk-416)
__global__ void k_tabs1(_Float16* __restrict__ Bh, _Float16* __restrict__ Bl) {
  int idx = blockIdx.x * blockDim.x + threadIdx.x;
  if (idx >= NCOLS * KCAT) return;
  int n = idx / KCAT, kk = idx - n * KCAT;
  double v = 0.0;
  if (n <= 400) {
    if (kk < KHALF) {
      int k = kk;
      if (k <= 400) {
        double ak = (k == 0 || k == 400) ? 1.0 : 2.0;
        int ph = (k * n) % NFFT;
        v = 16.0 * ak * cos((double)ph * (TWO_PI_D / 800.0));
      }
    } else {
      int k = kk - KHALF;
      if (k <= 400) {
        int ph = (k * n) % NFFT;
        v = -32.0 * sin((double)ph * (TWO_PI_D / 800.0));
      }
    }
  }
  float vf = (float)v;
  _Float16 h = (_Float16)vf;
  Bh[idx] = h;
  Bl[idx] = (_Float16)((vf - (float)h) * 2048.0f);
}

// B2 [kf=freq col 0..447][kk 0..831]: kk<416: cos(2pi kf nt/800) (nt=kk)
//                                     kk>=416: -sin(2pi kf nt/800) (nt=kk-416)
__global__ void k_tabs2(_Float16* __restrict__ Bh, _Float16* __restrict__ Bl) {
  int idx = blockIdx.x * blockDim.x + threadIdx.x;
  if (idx >= NCOLS * KCAT) return;
  int kf = idx / KCAT, kk = idx - kf * KCAT;
  double v = 0.0;
  if (kf <= 400) {
    if (kk < KHALF) {
      int nt = kk;
      if (nt <= 400) {
        int ph = (kf * nt) % NFFT;
        v = cos((double)ph * (TWO_PI_D / 800.0));
      }
    } else {
      int nt = kk - KHALF;
      if (nt <= 400) {
        int ph = (kf * nt) % NFFT;
        v = -sin((double)ph * (TWO_PI_D / 800.0));
      }
    }
  }
  float vf = (float)v;
  _Float16 h = (_Float16)vf;
  Bh[idx] = h;
  Bl[idx] = (_Float16)((vf - (float)h) * 2048.0f);
}

// ---------------- InverseMelScale: 50 SGD iterations, 1 wave per row ----------------
__global__ __launch_bounds__(64) void k_sgd(
    const float* __restrict__ spec0, const float* __restrict__ xmel,
    const float* __restrict__ fbT, const int* __restrict__ mlo,
    const int* __restrict__ mhi, const int* __restrict__ fm0,
    const float* __restrict__ fw0, const float* __restrict__ fw1,
    float* __restrict__ mag) {
  __shared__ float s_spec[NFREQ], s_vel[NFREQ], s_diff[NMELS], s_mel[NMELS];
  const int row = blockIdx.x;
  const int b = row / TT, t = row - b * TT;
  const int tid = threadIdx.x;
  for (int f = tid; f < NFREQ; f += 64) { s_spec[f] = spec0[row * NFREQ + f]; s_vel[f] = 0.f; }
  for (int m = tid; m < NMELS; m += 64) s_mel[m] = xmel[(b * NMELS + m) * TT + t];
  __syncthreads();
  for (int it = 0; it < SGDITERS; ++it) {
    for (int m = tid; m < NMELS; m += 64) {
      float acc = 0.f;
      const int lo = mlo[m], hi = mhi[m];
      const float* fr = fbT + m * NFREQ;
      for (int f = lo; f < hi; ++f) acc = fmaf(s_spec[f], fr[f], acc);
      s_diff[m] = s_mel[m] - acc;
    }
    __syncthreads();
    for (int f = tid; f < NFREQ; f += 64) {
      int m0 = fm0[f];
      int m1 = m0 + 1; if (m1 > NMELS - 1) m1 = NMELS - 1;
      float d = s_diff[m0] * fw0[f] + s_diff[m1] * fw1[f];
      float g = -SGD_SCALE * d;
      float v = 0.9f * s_vel[f] + g;
      s_vel[f] = v;
      float sp = s_spec[f] - 0.1f * v;
      s_spec[f] = sp > 0.f ? sp : 0.f;
    }
    __syncthreads();
  }
  for (int f = tid; f < NFREQ; f += 64) mag[row * NFREQ + f] = sqrtf(s_spec[f]);
}

// ---------------- A1 prep (iteration 0; layout [Re@0|Im@416], pads zeroed) --------
__global__ void k_prep1(const float* __restrict__ mag, const float* __restrict__ ar,
                        const float* __restrict__ ai,
                        _Float16* __restrict__ Ah, _Float16* __restrict__ Al) {
  int kk = blockIdx.x * 256 + threadIdx.x;
  if (kk >= KCAT) return;
  int row = blockIdx.y;
  float v = 0.f;
  if (kk < KHALF) {
    int k = kk;
    if (k <= 400) { int gi = row * NFREQ + k; v = mag[gi] * ar[gi] * 256.0f; }
  } else {
    int k = kk - KHALF;
    if (k <= 400) { int gi = row * NFREQ + k; v = mag[gi] * ai[gi] * 256.0f; }
  }
  _Float16 h = (_Float16)v;
  size_t o = (size_t)row * KCAT + kk;
  Ah[o] = h;
  Al[o] = (_Float16)((v - (float)h) * 2048.0f);
}

// ---------------- shared GEMM compute macro ----------------
// per chunk: read a frags, then 3-MFMA into the given acc set (hi, lo-corr)
#define GEMM_COMPUTE(A0, A1v)                                                   \
  {                                                                             \
    half8 a_h[2], a_l[2];                                                       \
    _Pragma("unroll")                                                           \
    for (int i = 0; i < 2; ++i) {                                               \
      int m = wm * 32 + i * 16 + lm;                                            \
      a_h[i] = *(const half8*)&As_h[m * 40 + qd * 8];                           \
      a_l[i] = *(const half8*)&As_l[m * 40 + qd * 8];                           \
    }                                                                           \
    _Pragma("unroll")                                                           \
    for (int j = 0; j < 2; ++j) {                                               \
      int n = wn * 32 + j * 16 + lm;                                            \
      half8 b_h = *(const half8*)&Bs_h[n * 40 + qd * 8];                        \
      half8 b_l = *(const half8*)&Bs_l[n * 40 + qd * 8];                        \
      _Pragma("unroll")                                                         \
      for (int i = 0; i < 2; ++i) {                                             \
        A0[i][j]  = __builtin_amdgcn_mfma_f32_16x16x32_f16(a_h[i], b_h, A0[i][j], 0, 0, 0);  \
        A1v[i][j] = __builtin_amdgcn_mfma_f32_16x16x32_f16(a_h[i], b_l, A1v[i][j], 0, 0, 0); \
        A1v[i][j] = __builtin_amdgcn_mfma_f32_16x16x32_f16(a_l[i], b_h, A1v[i][j], 0, 0, 0); \
      }                                                                         \
    }                                                                           \
  }

// staging + prefetch loop shared by mm1/mm2 (K=832, 26 chunks, split at 13)
#define GEMM_LOOP                                                               \
  uint4 pa_h = *(const uint4*)&Ah[abase];                                       \
  uint4 pa_l = *(const uint4*)&Al[abase];                                       \
  uint4 pb_h = *(const uint4*)&Bh[bbase];                                       \
  uint4 pb_l = *(const uint4*)&Bl[bbase];                                       \
  for (int c = 0; c < 26; ++c) {                                                \
    *(uint4*)&As_h[sr * 40 + sk] = pa_h;                                        \
    *(uint4*)&As_l[sr * 40 + sk] = pa_l;                                        \
    *(uint4*)&Bs_h[sr * 40 + sk] = pb_h;                                        \
    *(uint4*)&Bs_l[sr * 40 + sk] = pb_l;                                        \
    __syncthreads();                                                            \
    if (c < 25) {                                                               \
      int off = (c + 1) * 32;                                                   \
      pa_h = *(const uint4*)&Ah[abase + off];                                   \
      pa_l = *(const uint4*)&Al[abase + off];                                   \
      pb_h = *(const uint4*)&Bh[bbase + off];                                   \
      pb_l = *(const uint4*)&Bl[bbase + off];                                   \
    }                                                                           \
    if (c < 13) { GEMM_COMPUTE(ac0, ac1) } else { GEMM_COMPUTE(as0, as1) }      \
    __syncthreads();                                                            \
  }

// ---------------- mm1: frames via C/S symmetric irfft ----------------
// 64x64 tile, 4 waves 2x2 of 32x32; grid (7,64)
__global__ __launch_bounds__(256, 2) void k_mm1(
    const _Float16* __restrict__ Ah, const _Float16* __restrict__ Al,
    const _Float16* __restrict__ Bh, const _Float16* __restrict__ Bl,
    const float* __restrict__ win, float* __restrict__ frames) {
  __shared__ __align__(16) _Float16 As_h[64 * 40], As_l[64 * 40];
  __shared__ __align__(16) _Float16 Bs_h[64 * 40], Bs_l[64 * 40];
  const int t = threadIdx.x;
  const int row0 = blockIdx.y * 64;
  const int col0 = blockIdx.x * 64;
  const int sr = t >> 2, sk = (t & 3) * 8;
  const int lane = t & 63, wv = t >> 6;
  const int wm = wv & 1, wn = wv >> 1;
  const int lm = lane & 15, qd = lane >> 4;
  f32x4 ac0[2][2] = {}, ac1[2][2] = {}, as0[2][2] = {}, as1[2][2] = {};
  const size_t abase = (size_t)(row0 + sr) * KCAT + sk;
  const size_t bbase = (size_t)(col0 + sr) * KCAT + sk;
  GEMM_LOOP
#pragma unroll
  for (int j = 0; j < 2; ++j) {
    int col = col0 + wn * 32 + j * 16 + lm;
    if (col <= 400) {
      float wA = win[col];
      bool mir = (col >= 1 && col <= 399);
      float wB = mir ? win[800 - col] : 0.f;
#pragma unroll
      for (int i = 0; i < 2; ++i)
#pragma unroll
        for (int r = 0; r < 4; ++r) {
          int row = row0 + wm * 32 + i * 16 + qd * 4 + r;
          float Cv = ac0[i][j][r] + ac1[i][j][r] * LO_INV;
          float Sv = as0[i][j][r] + as1[i][j][r] * LO_INV;
          frames[(size_t)row * NFFT + col] = (Cv + Sv) * wA;
          if (mir) frames[(size_t)row * NFFT + (800 - col)] = (Cv - Sv) * wB;
        }
    }
  }
}

// ---------------- fused OLA + window + E/O split prep ----------------
__device__ inline float sample_y(const float* __restrict__ fb_,
                                 const float* __restrict__ wsqs, int j) {
  int jm = (j < PADW) ? (NFFT - j) : ((j < PADW + LOUTW) ? j : (205198 - j));
  int t1 = jm / HOPSZ; if (t1 > TT - 1) t1 = TT - 1;
  int t0 = (jm - (NFFT - HOPSZ)) / HOPSZ; if (t0 < 0) t0 = 0;
  float s = 0.f;
  for (int t = t0; t <= t1; ++t) s += fb_[t * NFFT + (jm - t * HOPSZ)];
  return s / wsqs[jm];
}

__global__ void k_olaprep(const float* __restrict__ frames, const float* __restrict__ wsqs,
                          const float* __restrict__ win,
                          _Float16* __restrict__ A2h, _Float16* __restrict__ A2l) {
  int idx = blockIdx.x * 256 + threadIdx.x;      // row*416 + n
  if (idx >= NROWS * KHALF) return;
  int row = idx / KHALF, n = idx - row * KHALF;
  size_t ab = (size_t)row * KCAT;
  if (n > 400) {                                  // K pads
    A2h[ab + n] = (_Float16)0.f; A2l[ab + n] = (_Float16)0.f;
    A2h[ab + KHALF + n] = (_Float16)0.f; A2l[ab + KHALF + n] = (_Float16)0.f;
    return;
  }
  int b = row >> 9, tt = row & 511;
  const float* fb_ = frames + (size_t)b * TT * NFFT;
  int start = tt * HOPSZ;
  float x1 = sample_y(fb_, wsqs, start + n) * win[n] * 256.0f;
  float x2 = 0.f;
  // mirror only for n in [1,399]: n==400 maps to itself (800-400==400) and
  // n==0's mirror (800) is outside the frame -- both must NOT be added.
  if (n >= 1 && n <= 399)
    x2 = sample_y(fb_, wsqs, start + 800 - n) * win[800 - n] * 256.0f;
  float E = x1 + x2, O = x1 - x2;
  _Float16 Eh = (_Float16)E;
  A2h[ab + n] = Eh;
  A2l[ab + n] = (_Float16)((E - (float)Eh) * 2048.0f);
  _Float16 Oh = (_Float16)O;
  A2h[ab + KHALF + n] = Oh;
  A2l[ab + KHALF + n] = (_Float16)((O - (float)Oh) * 2048.0f);
}

// ---------------- mm2: rfft (Re/Im symmetric) + momentum + normalize + A1' -------
__global__ __launch_bounds__(256, 2) void k_mm2(
    const _Float16* __restrict__ Ah, const _Float16* __restrict__ Al,
    const _Float16* __restrict__ Bh, const _Float16* __restrict__ Bl,
    const float* __restrict__ mag,
    float* __restrict__ tppr, float* __restrict__ tppi,
    _Float16* __restrict__ A1h, _Float16* __restrict__ A1l, float beta) {
  __shared__ __align__(16) _Float16 As_h[64 * 40], As_l[64 * 40];
  __shared__ __align__(16) _Float16 Bs_h[64 * 40], Bs_l[64 * 40];
  const int t = threadIdx.x;
  const int row0 = blockIdx.y * 64;
  const int col0 = blockIdx.x * 64;
  const int sr = t >> 2, sk = (t & 3) * 8;
  const int lane = t & 63, wv = t >> 6;
  const int wm = wv & 1, wn = wv >> 1;
  const int lm = lane & 15, qd = lane >> 4;
  f32x4 ac0[2][2] = {}, ac1[2][2] = {}, as0[2][2] = {}, as1[2][2] = {};
  const size_t abase = (size_t)(row0 + sr) * KCAT + sk;
  const size_t bbase = (size_t)(col0 + sr) * KCAT + sk;
  GEMM_LOOP
#pragma unroll
  for (int j = 0; j < 2; ++j) {
    int col = col0 + wn * 32 + j * 16 + lm;
    if (col <= 400) {
#pragma unroll
      for (int i = 0; i < 2; ++i)
#pragma unroll
        for (int r = 0; r < 4; ++r) {
          int row = row0 + wm * 32 + i * 16 + qd * 4 + r;
          int idx = row * NFREQ + col;
          float rr = ac0[i][j][r] + ac1[i][j][r] * LO_INV;   // Re (x256 scale)
          float ri = as0[i][j][r] + as1[i][j][r] * LO_INV;   // Im
          float nr = rr - beta * tppr[idx];
          float ni = ri - beta * tppi[idx];
          tppr[idx] = rr; tppi[idx] = ri;
          float den = sqrtf(nr * nr + ni * ni) + 1e-16f;
          float arv = nr / den, aiv = ni / den;
          float mg = mag[idx] * 256.0f;
          size_t ab = (size_t)row * KCAT;
          float v1 = mg * arv;
          _Float16 h1 = (_Float16)v1;
          A1h[ab + col] = h1;
          A1l[ab + col] = (_Float16)((v1 - (float)h1) * 2048.0f);
          float v2 = mg * aiv;
          _Float16 h2 = (_Float16)v2;
          A1h[ab + KHALF + col] = h2;
          A1l[ab + KHALF + col] = (_Float16)((v2 - (float)h2) * 2048.0f);
        }
    }
  }
}

// ---------------- final overlap-add (full y, once) ----------------
__global__ void k_ola(const float* __restrict__ frames, const float* __restrict__ wsqs,
                      float* __restrict__ y) {
  int idx = blockIdx.x * blockDim.x + threadIdx.x;
  if (idx >= NB * LY) return;
  int b = idx / LY, j = idx - b * LY;
  int t1 = j / HOPSZ; if (t1 > TT - 1) t1 = TT - 1;
  int t0 = (j - (NFFT - HOPSZ)) / HOPSZ; if (t0 < 0) t0 = 0;
  const float* fb_ = frames + (size_t)b * TT * NFFT;
  float s = 0.f;
  for (int t = t0; t <= t1; ++t) s += fb_[t * NFFT + (j - t * HOPSZ)];
  y[idx] = s / wsqs[j];
}

// ---------------- epilogue: peak-normalize ----------------
__global__ void k_absmax(const float* __restrict__ y, float* __restrict__ peak) {
  __shared__ float red[256];
  int b = blockIdx.x;
  const float* yb = y + (size_t)b * LY + PADW;
  float mx = 0.f;
  for (int j = threadIdx.x; j < LOUTW; j += 256) mx = fmaxf(mx, fabsf(yb[j]));
  red[threadIdx.x] = mx;
  __syncthreads();
  for (int s2 = 128; s2 > 0; s2 >>= 1) {
    if (threadIdx.x < s2) red[threadIdx.x] = fmaxf(red[threadIdx.x], red[threadIdx.x + s2]);
    __syncthreads();
  }
  if (threadIdx.x == 0) peak[b] = red[0];
}

__global__ void k_scale(const float* __restrict__ y, const float* __restrict__ peak,
                        float* __restrict__ out, float target) {
  int idx = blockIdx.x * blockDim.x + threadIdx.x;
  if (idx >= NB * LOUTW) return;
  int b = idx / LOUTW, j = idx - b * LOUTW;
  out[idx] = y[(size_t)b * LY + PADW + j] * (target / peak[b]);
}

__global__ void k_zero2(float* __restrict__ a, float* __restrict__ b, int n) {
  int i = blockIdx.x * blockDim.x + threadIdx.x;
  if (i < n) { a[i] = 0.f; b[i] = 0.f; }
}

// ---------------- host ----------------
extern "C" void kernel_launch(void* const* d_in, const int* in_sizes, int n_in,
                              void* d_out, int out_size, void* d_ws, size_t ws_size,
                              hipStream_t stream) {
  const float* xmel = (const float*)d_in[0];   // (8, 80, 512) f32
  float* out = (float*)d_out;                  // (8, 1, 102200) f32

  char* p = (char*)d_ws;
  auto alloc = [&](size_t nbytes) -> void* {
    void* r = (void*)p;
    p += (nbytes + 255) & ~(size_t)255;
    return r;
  };
  float* mag  = (float*)alloc((size_t)NSPEC * 4);
  float* ar   = (float*)alloc((size_t)NSPEC * 4);
  float* ai   = (float*)alloc((size_t)NSPEC * 4);
  float* tpr  = (float*)alloc((size_t)NSPEC * 4);
  float* tpi  = (float*)alloc((size_t)NSPEC * 4);
  float* y    = (float*)alloc((size_t)NB * LY * 4);
  float* win  = (float*)alloc(NFFT * 4);
  float* wsqs = (float*)alloc((size_t)LY * 4);
  float* fbT  = (float*)alloc((size_t)NMELS * NFREQ * 4);
  float* fw0  = (float*)alloc(NFREQ * 4);
  float* fw1  = (float*)alloc(NFREQ * 4);
  float* peak = (float*)alloc(NB * 4);
  int* fm0    = (int*)alloc(NFREQ * 4);
  int* mlo    = (int*)alloc(NMELS * 4);
  int* mhi    = (int*)alloc(NMELS * 4);
  float* frames = (float*)alloc((size_t)NROWS * NFFT * 4);
  float* spec0 = frames;  // alias: consumed by k_sgd before frames written
  _Float16* A1h = (_Float16*)alloc((size_t)NROWS * KCAT * 2);
  _Float16* A1l = (_Float16*)alloc((size_t)NROWS * KCAT * 2);
  _Float16* A2h = (_Float16*)alloc((size_t)NROWS * KCAT * 2);
  _Float16* A2l = (_Float16*)alloc((size_t)NROWS * KCAT * 2);
  _Float16* B1h = (_Float16*)alloc((size_t)NCOLS * KCAT * 2);
  _Float16* B1l = (_Float16*)alloc((size_t)NCOLS * KCAT * 2);
  _Float16* B2h = (_Float16*)alloc((size_t)NCOLS * KCAT * 2);
  _Float16* B2l = (_Float16*)alloc((size_t)NCOLS * KCAT * 2);

  if ((size_t)(p - (char*)d_ws) > ws_size) return;  // insufficient scratch

  // derived threefry keys (jax partitionable split)
  unsigned k1a, k1b, k2a, k2b, kra, krb, kia, kib;
  {
    unsigned o0, o1;
    tf2x32(0u, 1u, 0u, 0u, o0, o1); k1a = o0; k1b = o1;
    tf2x32(0u, 1u, 0u, 1u, o0, o1); k2a = o0; k2b = o1;
    tf2x32(k2a, k2b, 0u, 0u, o0, o1); kra = o0; krb = o1;
    tf2x32(k2a, k2b, 0u, 1u, o0, o1); kia = o0; kib = o1;
  }

  // init
  k_fb<<<2, 256, 0, stream>>>(fbT, fm0, fw0, fw1);
  k_ranges<<<1, 128, 0, stream>>>(fbT, mlo, mhi);
  k_wsq<<<(LY + 255) / 256, 256, 0, stream>>>(wsqs, win);
  k_tabs1<<<(NCOLS * KCAT + 255) / 256, 256, 0, stream>>>(B1h, B1l);
  k_tabs2<<<(NCOLS * KCAT + 255) / 256, 256, 0, stream>>>(B2h, B2l);
  k_zero2<<<(NSPEC + 255) / 256, 256, 0, stream>>>(tpr, tpi, NSPEC);
  k_rand_spec<<<(NSPEC + 255) / 256, 256, 0, stream>>>(k1a, k1b, spec0);
  k_rand_ang<<<(NSPEC + 255) / 256, 256, 0, stream>>>(kra, krb, kia, kib, ar, ai);

  // InverseMelScale (1 wave per (b,t) row)
  k_sgd<<<NROWS, 64, 0, stream>>>(spec0, xmel, fbT, mlo, mhi, fm0, fw0, fw1, mag);

  // iteration-0 A1 (layout [Re@0|Im@416], pads zeroed once)
  k_prep1<<<dim3(4, NROWS), 256, 0, stream>>>(mag, ar, ai, A1h, A1l);

  // Griffin-Lim: 3 dispatches per iteration
  const float beta = (float)(0.99 / 1.99);
  for (int it = 0; it < GLITERS; ++it) {
    k_mm1<<<dim3(7, 64), 256, 0, stream>>>(A1h, A1l, B1h, B1l, win, frames);
    k_olaprep<<<(NROWS * KHALF + 255) / 256, 256, 0, stream>>>(frames, wsqs, win, A2h, A2l);
    k_mm2<<<dim3(7, 64), 256, 0, stream>>>(A2h, A2l, B2h, B2l,
                                           mag, tpr, tpi, A1h, A1l, beta);
  }
  // final istft with final angles (A1 written by last k_mm2)
  k_mm1<<<dim3(7, 64), 256, 0, stream>>>(A1h, A1l, B1h, B1l, win, frames);
  k_ola<<<(NB * LY + 255) / 256, 256, 0, stream>>>(frames, wsqs, y);

  // normalize
  k_absmax<<<NB, 256, 0, stream>>>(y, peak);
  const float target = (float)pow(10.0, -0.1 / 20.0);
  k_scale<<<(NB * LOUTW + 255) / 256, 256, 0, stream>>>(y, peak, out, target);
}

// Round 10
// 2522.876 us; speedup vs baseline: 2.1354x; 1.0752x over previous
//
#include <hip/hip_runtime.h>
#include <math.h>

// ---------------- problem constants ----------------
#define NB 8
#define NMELS 80
#define TT 512
#define NFREQ 401
#define NFFT 800
#define HOPSZ 200
#define NROWS (NB*TT)          // 4096 frames
#define LY 103000              // untrimmed istft length
#define LOUTW 102200
#define PADW 400
#define NSPEC (NROWS*NFREQ)    // 1640448
#define GLITERS 30
#define SGDITERS 50
#define SGD_SCALE 0.003125f    // 2/(B*n_mels)
#define KCAT 832               // concatenated K: [part0 416 | part1 416]
#define KHALF 416
#define NCOLS 448              // padded output cols (7*64), valid [0,400]
#define MAXSPAN 24             // max mel-band width in bins (measured 21)
// scales: A x256, B1 x16 (/800 dropped), lo parts x2048
#define WSQ_SCALE 3276800.0f   // 800*16*256
#define LO_INV 4.8828125e-4f   // 2^-11

#define TWO_PI_D 6.283185307179586476925286766559

typedef _Float16 half8 __attribute__((ext_vector_type(8)));
typedef float f32x4 __attribute__((ext_vector_type(4)));

// ---------------- threefry2x32 (20 rounds) ----------------
__host__ __device__ inline void tf2x32(unsigned k0, unsigned k1,
                                       unsigned x0, unsigned x1,
                                       unsigned& o0, unsigned& o1) {
  unsigned ks0 = k0, ks1 = k1, ks2 = k0 ^ k1 ^ 0x1BD11BDAu;
  x0 += ks0; x1 += ks1;
#define TF_R(r) { x0 += x1; x1 = (x1 << (r)) | (x1 >> (32 - (r))); x1 ^= x0; }
  TF_R(13) TF_R(15) TF_R(26) TF_R(6)
  x0 += ks1; x1 += ks2 + 1u;
  TF_R(17) TF_R(29) TF_R(16) TF_R(24)
  x0 += ks2; x1 += ks0 + 2u;
  TF_R(13) TF_R(15) TF_R(26) TF_R(6)
  x0 += ks0; x1 += ks1 + 3u;
  TF_R(17) TF_R(29) TF_R(16) TF_R(24)
  x0 += ks1; x1 += ks2 + 4u;
  TF_R(13) TF_R(15) TF_R(26) TF_R(6)
  x0 += ks2; x1 += ks0 + 5u;
#undef TF_R
  o0 = x0; o1 = x1;
}

__device__ inline float u01(unsigned bits) {
  unsigned u = (bits >> 9) | 0x3f800000u;
  return __uint_as_float(u) - 1.0f;
}

__device__ inline int ang_map(int g) {
  int b = g / (NFREQ * TT);
  int r = g - b * (NFREQ * TT);
  int f = r / TT;
  int t = r - f * TT;
  return (b * TT + t) * NFREQ + f;
}

__global__ void k_rand_spec(unsigned ka, unsigned kb, float* __restrict__ spec) {
  int i = blockIdx.x * blockDim.x + threadIdx.x;
  if (i >= NSPEC) return;
  unsigned o0, o1; tf2x32(ka, kb, 0u, (unsigned)i, o0, o1);
  spec[i] = u01(o0 ^ o1);    // partitionable 32-bit fold
}

__global__ void k_rand_ang(unsigned kra, unsigned krb, unsigned kia, unsigned kib,
                           float* __restrict__ ar, float* __restrict__ ai) {
  int g = blockIdx.x * blockDim.x + threadIdx.x;
  if (g >= NSPEC) return;
  int d = ang_map(g);
  unsigned o0, o1;
  tf2x32(kra, krb, 0u, (unsigned)g, o0, o1); ar[d] = u01(o0 ^ o1);
  tf2x32(kia, kib, 0u, (unsigned)g, o0, o1); ai[d] = u01(o0 ^ o1);
}

// ---------------- mel filterbank ----------------
__device__ inline double mel2hz_d(double mel) {
  return 700.0 * (pow(10.0, mel / 2595.0) - 1.0);
}

__global__ void k_fb(float* __restrict__ fbT, int* __restrict__ fm0,
                     float* __restrict__ fw0, float* __restrict__ fw1) {
  int f = blockIdx.x * blockDim.x + threadIdx.x;
  if (f >= NFREQ) return;
  const double freq = 10.0 * (double)f;
  const double melmax = 2595.0 * log10(1.0 + 4000.0 / 700.0);
  const double step = melmax / 81.0;
  int first = -1; float w0v = 0.f, w1v = 0.f;
  double p0 = 0.0;
  double p1 = mel2hz_d(step);
  for (int m = 0; m < NMELS; ++m) {
    double m2 = (m + 2 == 81) ? melmax : (double)(m + 2) * step;
    double p2 = mel2hz_d(m2);
    double down = (freq - p0) / (p1 - p0);
    double up   = (p2 - freq) / (p2 - p1);
    double v = down < up ? down : up;
    if (v < 0.0) v = 0.0;
    float vf = (float)v;
    fbT[m * NFREQ + f] = vf;
    if (vf > 0.f) {
      if (first < 0) { first = m; w0v = vf; }
      else if (m == first + 1) { w1v = vf; }
    }
    p0 = p1; p1 = p2;
  }
  fm0[f] = first < 0 ? 0 : first;
  fw0[f] = first < 0 ? 0.f : w0v;
  fw1[f] = w1v;
}

__global__ void k_ranges(const float* __restrict__ fbT, int* __restrict__ mlo,
                         int* __restrict__ mhi) {
  int m = threadIdx.x;
  if (m >= NMELS) return;
  int lo = NFREQ, hi = 0;
  for (int f = 0; f < NFREQ; ++f)
    if (fbT[m * NFREQ + f] > 0.f) { if (lo == NFREQ) lo = f; hi = f + 1; }
  mlo[m] = lo; mhi[m] = hi < lo ? lo : hi;
}

// ---------------- window + OLA weight (pre-scaled) + reciprocal ----------------
__device__ inline double hann_d(int i) {
  return 0.5 - 0.5 * cos(TWO_PI_D * (double)i / 800.0);
}

__global__ void k_wsq(float* __restrict__ wsqs, float* __restrict__ wsinv,
                      float* __restrict__ win) {
  int j = blockIdx.x * blockDim.x + threadIdx.x;
  if (j >= LY) return;
  if (j < NFFT) win[j] = (float)hann_d(j);
  int t1 = j / HOPSZ; if (t1 > TT - 1) t1 = TT - 1;
  int t0 = (j - (NFFT - HOPSZ)) / HOPSZ; if (t0 < 0) t0 = 0;
  float s = 0.f;
  for (int t = t0; t <= t1; ++t) {
    float w = (float)hann_d(j - t * HOPSZ);
    s += w * w;
  }
  s = fmaxf(s, 1e-11f);
  wsqs[j] = WSQ_SCALE * s;
  wsinv[j] = (float)(1.0 / ((double)WSQ_SCALE * (double)s));  // single rounding
}

// ---------------- symmetric f16-split DFT tables ----------------
// B1 [n=time col 0..447][kk 0..831]: kk<416: 16*ak*cos(2pi k n/800) (k=kk)
//                                    kk>=416: -32*sin(2pi k n/800) (k=kk-416)
__global__ void k_tabs1(_Float16* __restrict__ Bh, _Float16* __restrict__ Bl) {
  int idx = blockIdx.x * blockDim.x + threadIdx.x;
  if (idx >= NCOLS * KCAT) return;
  int n = idx / KCAT, kk = idx - n * KCAT;
  double v = 0.0;
  if (n <= 400) {
    if (kk < KHALF) {
      int k = kk;
      if (k <= 400) {
        double ak = (k == 0 || k == 400) ? 1.0 : 2.0;
        int ph = (k * n) % NFFT;
        v = 16.0 * ak * cos((double)ph * (TWO_PI_D / 800.0));
      }
    } else {
      int k = kk - KHALF;
      if (k <= 400) {
        int ph = (k * n) % NFFT;
        v = -32.0 * sin((double)ph * (TWO_PI_D / 800.0));
      }
    }
  }
  float vf = (float)v;
  _Float16 h = (_Float16)vf;
  Bh[idx] = h;
  Bl[idx] = (_Float16)((vf - (float)h) * 2048.0f);
}

// B2 [kf=freq col 0..447][kk 0..831]: kk<416: cos(2pi kf nt/800) (nt=kk)
//                                     kk>=416: -sin(2pi kf nt/800) (nt=kk-416)
__global__ void k_tabs2(_Float16* __restrict__ Bh, _Float16* __restrict__ Bl) {
  int idx = blockIdx.x * blockDim.x + threadIdx.x;
  if (idx >= NCOLS * KCAT) return;
  int kf = idx / KCAT, kk = idx - kf * KCAT;
  double v = 0.0;
  if (kf <= 400) {
    if (kk < KHALF) {
      int nt = kk;
      if (nt <= 400) {
        int ph = (kf * nt) % NFFT;
        v = cos((double)ph * (TWO_PI_D / 800.0));
      }
    } else {
      int nt = kk - KHALF;
      if (nt <= 400) {
        int ph = (kf * nt) % NFFT;
        v = -sin((double)ph * (TWO_PI_D / 800.0));
      }
    }
  }
  float vf = (float)v;
  _Float16 h = (_Float16)vf;
  Bh[idx] = h;
  Bl[idx] = (_Float16)((vf - (float)h) * 2048.0f);
}

// ---------------- InverseMelScale: register-resident SGD, 1 wave per row --------
// All loop-invariant data (fb rows, per-f weights) preloaded into registers;
// vel/spec in registers; only s_spec / s_diff round-trip through LDS.
// FMA order identical to prior version -> bit-identical result.
__global__ __launch_bounds__(64) void k_sgd(
    const float* __restrict__ spec0, const float* __restrict__ xmel,
    const float* __restrict__ fbT, const int* __restrict__ mlo,
    const int* __restrict__ mhi, const int* __restrict__ fm0,
    const float* __restrict__ fw0, const float* __restrict__ fw1,
    float* __restrict__ mag) {
  __shared__ float s_spec[NFREQ], s_diff[NMELS];
  const int row = blockIdx.x;
  const int b = row / TT, t = row - b * TT;
  const int tid = threadIdx.x;

  // per-f register state (f = tid + 64q, q<7)
  float spec[7], vel[7];
  int qm0[7], qm1[7];
  float qw0[7], qw1[7];
#pragma unroll
  for (int q = 0; q < 7; ++q) {
    int f = tid + 64 * q;
    bool v = f < NFREQ;
    float sv = v ? spec0[row * NFREQ + f] : 0.f;
    spec[q] = sv; vel[q] = 0.f;
    if (v) s_spec[f] = sv;
    int m0 = v ? fm0[f] : 0;
    int m1 = m0 + 1; if (m1 > NMELS - 1) m1 = NMELS - 1;
    qm0[q] = m0; qm1[q] = m1;
    qw0[q] = v ? fw0[f] : 0.f;
    qw1[q] = v ? fw1[f] : 0.f;
  }

  // per-mel register state: thread handles mA=tid and (if valid) mB=tid+64
  const int mA = tid;
  const int mB = tid + 64;
  const bool hasB = mB < NMELS;
  float melA = xmel[(b * NMELS + mA) * TT + t];
  float melB = hasB ? xmel[(b * NMELS + mB) * TT + t] : 0.f;
  int loA = mlo[mA];
  int hiA = mhi[mA];
  int loB = hasB ? mlo[mB] : 0;
  int hiB = hasB ? mhi[mB] : 0;
  float fbA[MAXSPAN], fbB[MAXSPAN];
#pragma unroll
  for (int i = 0; i < MAXSPAN; ++i) {
    fbA[i] = (loA + i < hiA) ? fbT[mA * NFREQ + loA + i] : 0.f;
    fbB[i] = (hasB && loB + i < hiB) ? fbT[mB * NFREQ + loB + i] : 0.f;
  }
  __syncthreads();

  for (int it = 0; it < SGDITERS; ++it) {
    float accA = 0.f, accB = 0.f;
#pragma unroll
    for (int i = 0; i < MAXSPAN; ++i) {
      int fA = loA + i; if (fA > 400) fA = 400;
      int fB = loB + i; if (fB > 400) fB = 400;
      accA = fmaf(fbA[i], s_spec[fA], accA);   // fb==0 beyond span: exact no-op
      accB = fmaf(fbB[i], s_spec[fB], accB);
    }
    s_diff[mA] = melA - accA;
    if (hasB) s_diff[mB] = melB - accB;
    __syncthreads();
#pragma unroll
    for (int q = 0; q < 7; ++q) {
      int f = tid + 64 * q;
      if (f < NFREQ) {
        float d = s_diff[qm0[q]] * qw0[q] + s_diff[qm1[q]] * qw1[q];
        float g = -SGD_SCALE * d;
        float v = 0.9f * vel[q] + g;
        vel[q] = v;
        float sp = spec[q] - 0.1f * v;
        sp = sp > 0.f ? sp : 0.f;
        spec[q] = sp;
        s_spec[f] = sp;
      }
    }
    __syncthreads();
  }
#pragma unroll
  for (int q = 0; q < 7; ++q) {
    int f = tid + 64 * q;
    if (f < NFREQ) mag[row * NFREQ + f] = sqrtf(spec[q]);
  }
}

// ---------------- A1 prep (iteration 0; layout [Re@0|Im@416], pads zeroed) --------
__global__ void k_prep1(const float* __restrict__ mag, const float* __restrict__ ar,
                        const float* __restrict__ ai,
                        _Float16* __restrict__ Ah, _Float16* __restrict__ Al) {
  int kk = blockIdx.x * 256 + threadIdx.x;
  if (kk >= KCAT) return;
  int row = blockIdx.y;
  float v = 0.f;
  if (kk < KHALF) {
    int k = kk;
    if (k <= 400) { int gi = row * NFREQ + k; v = mag[gi] * ar[gi] * 256.0f; }
  } else {
    int k = kk - KHALF;
    if (k <= 400) { int gi = row * NFREQ + k; v = mag[gi] * ai[gi] * 256.0f; }
  }
  _Float16 h = (_Float16)v;
  size_t o = (size_t)row * KCAT + kk;
  Ah[o] = h;
  Al[o] = (_Float16)((v - (float)h) * 2048.0f);
}

// ---------------- shared GEMM macros (double-buffered, 1 barrier/chunk) ----------
#define GEMM_STAGE(BUF)                                                         \
    *(uint4*)&As_h[BUF][sr * 40 + sk] = pa_h;                                   \
    *(uint4*)&As_l[BUF][sr * 40 + sk] = pa_l;                                   \
    *(uint4*)&Bs_h[BUF][sr * 40 + sk] = pb_h;                                   \
    *(uint4*)&Bs_l[BUF][sr * 40 + sk] = pb_l;

#define GEMM_COMPUTE(BUF, A0, A1v)                                              \
  {                                                                             \
    half8 a_h[2], a_l[2];                                                       \
    _Pragma("unroll")                                                           \
    for (int i = 0; i < 2; ++i) {                                               \
      int m = wm * 32 + i * 16 + lm;                                            \
      a_h[i] = *(const half8*)&As_h[BUF][m * 40 + qd * 8];                      \
      a_l[i] = *(const half8*)&As_l[BUF][m * 40 + qd * 8];                      \
    }                                                                           \
    _Pragma("unroll")                                                           \
    for (int j = 0; j < 2; ++j) {                                               \
      int n = wn * 32 + j * 16 + lm;                                            \
      half8 b_h = *(const half8*)&Bs_h[BUF][n * 40 + qd * 8];                   \
      half8 b_l = *(const half8*)&Bs_l[BUF][n * 40 + qd * 8];                   \
      _Pragma("unroll")                                                         \
      for (int i = 0; i < 2; ++i) {                                             \
        A0[i][j]  = __builtin_amdgcn_mfma_f32_16x16x32_f16(a_h[i], b_h, A0[i][j], 0, 0, 0);  \
        A1v[i][j] = __builtin_amdgcn_mfma_f32_16x16x32_f16(a_h[i], b_l, A1v[i][j], 0, 0, 0); \
        A1v[i][j] = __builtin_amdgcn_mfma_f32_16x16x32_f16(a_l[i], b_h, A1v[i][j], 0, 0, 0); \
      }                                                                         \
    }                                                                           \
  }

// K=832, 26 chunks of 32; chunks 0..12 -> (ac0,ac1), 13..25 -> (as0,as1).
// Double-buffered: stage c+1 into buf^1 while computing from buf.
#define GEMM_LOOP                                                               \
  uint4 pa_h = *(const uint4*)&Ah[abase];                                       \
  uint4 pa_l = *(const uint4*)&Al[abase];                                       \
  uint4 pb_h = *(const uint4*)&Bh[bbase];                                       \
  uint4 pb_l = *(const uint4*)&Bl[bbase];                                       \
  GEMM_STAGE(0)                                                                 \
  _Pragma("unroll 2")                                                           \
  for (int c = 0; c < 26; ++c) {                                                \
    __syncthreads();                                                            \
    if (c < 25) {                                                               \
      int off = (c + 1) * 32;                                                   \
      pa_h = *(const uint4*)&Ah[abase + off];                                   \
      pa_l = *(const uint4*)&Al[abase + off];                                   \
      pb_h = *(const uint4*)&Bh[bbase + off];                                   \
      pb_l = *(const uint4*)&Bl[bbase + off];                                   \
    }                                                                           \
    const int bf = c & 1;                                                       \
    if (c < 13) { GEMM_COMPUTE(bf, ac0, ac1) } else { GEMM_COMPUTE(bf, as0, as1) } \
    if (c < 25) { GEMM_STAGE(bf ^ 1) }                                          \
  }

// ---------------- mm1: frames via C/S symmetric irfft ----------------
// 64x64 tile, 4 waves 2x2 of 32x32; grid (7,64)
__global__ __launch_bounds__(256, 2) void k_mm1(
    const _Float16* __restrict__ Ah, const _Float16* __restrict__ Al,
    const _Float16* __restrict__ Bh, const _Float16* __restrict__ Bl,
    const float* __restrict__ win, float* __restrict__ frames) {
  __shared__ __align__(16) _Float16 As_h[2][64 * 40], As_l[2][64 * 40];
  __shared__ __align__(16) _Float16 Bs_h[2][64 * 40], Bs_l[2][64 * 40];
  const int t = threadIdx.x;
  const int row0 = blockIdx.y * 64;
  const int col0 = blockIdx.x * 64;
  const int sr = t >> 2, sk = (t & 3) * 8;
  const int lane = t & 63, wv = t >> 6;
  const int wm = wv & 1, wn = wv >> 1;
  const int lm = lane & 15, qd = lane >> 4;
  f32x4 ac0[2][2] = {}, ac1[2][2] = {}, as0[2][2] = {}, as1[2][2] = {};
  const size_t abase = (size_t)(row0 + sr) * KCAT + sk;
  const size_t bbase = (size_t)(col0 + sr) * KCAT + sk;
  GEMM_LOOP
#pragma unroll
  for (int j = 0; j < 2; ++j) {
    int col = col0 + wn * 32 + j * 16 + lm;
    if (col <= 400) {
      float wA = win[col];
      bool mir = (col >= 1 && col <= 399);
      float wB = mir ? win[800 - col] : 0.f;
#pragma unroll
      for (int i = 0; i < 2; ++i)
#pragma unroll
        for (int r = 0; r < 4; ++r) {
          int row = row0 + wm * 32 + i * 16 + qd * 4 + r;
          float Cv = ac0[i][j][r] + ac1[i][j][r] * LO_INV;
          float Sv = as0[i][j][r] + as1[i][j][r] * LO_INV;
          frames[(size_t)row * NFFT + col] = (Cv + Sv) * wA;
          if (mir) frames[(size_t)row * NFFT + (800 - col)] = (Cv - Sv) * wB;
        }
    }
  }
}

// ---------------- fused OLA + window + E/O split prep ----------------
__device__ inline float sample_y(const float* __restrict__ fb_,
                                 const float* __restrict__ wsinv, int j) {
  int jm = (j < PADW) ? (NFFT - j) : ((j < PADW + LOUTW) ? j : (205198 - j));
  int t1 = jm / HOPSZ; if (t1 > TT - 1) t1 = TT - 1;
  int t0 = (jm - (NFFT - HOPSZ)) / HOPSZ; if (t0 < 0) t0 = 0;
  float s = 0.f;
  for (int t = t0; t <= t1; ++t) s += fb_[t * NFFT + (jm - t * HOPSZ)];
  return s * wsinv[jm];
}

__global__ void k_olaprep(const float* __restrict__ frames, const float* __restrict__ wsinv,
                          const float* __restrict__ win,
                          _Float16* __restrict__ A2h, _Float16* __restrict__ A2l) {
  int idx = blockIdx.x * 256 + threadIdx.x;      // row*416 + n
  if (idx >= NROWS * KHALF) return;
  int row = idx / KHALF, n = idx - row * KHALF;
  size_t ab = (size_t)row * KCAT;
  if (n > 400) {                                  // K pads
    A2h[ab + n] = (_Float16)0.f; A2l[ab + n] = (_Float16)0.f;
    A2h[ab + KHALF + n] = (_Float16)0.f; A2l[ab + KHALF + n] = (_Float16)0.f;
    return;
  }
  int b = row >> 9, tt = row & 511;
  const float* fb_ = frames + (size_t)b * TT * NFFT;
  int start = tt * HOPSZ;
  float x1 = sample_y(fb_, wsinv, start + n) * win[n] * 256.0f;
  float x2 = 0.f;
  // mirror only for n in [1,399]: n==400 maps to itself; n==0's mirror is OOB
  if (n >= 1 && n <= 399)
    x2 = sample_y(fb_, wsinv, start + 800 - n) * win[800 - n] * 256.0f;
  float E = x1 + x2, O = x1 - x2;
  _Float16 Eh = (_Float16)E;
  A2h[ab + n] = Eh;
  A2l[ab + n] = (_Float16)((E - (float)Eh) * 2048.0f);
  _Float16 Oh = (_Float16)O;
  A2h[ab + KHALF + n] = Oh;
  A2l[ab + KHALF + n] = (_Float16)((O - (float)Oh) * 2048.0f);
}

// ---------------- mm2: rfft (Re/Im symmetric) + momentum + normalize + A1' -------
__global__ __launch_bounds__(256, 2) void k_mm2(
    const _Float16* __restrict__ Ah, const _Float16* __restrict__ Al,
    const _Float16* __restrict__ Bh, const _Float16* __restrict__ Bl,
    const float* __restrict__ mag,
    float* __restrict__ tppr, float* __restrict__ tppi,
    _Float16* __restrict__ A1h, _Float16* __restrict__ A1l, float beta) {
  __shared__ __align__(16) _Float16 As_h[2][64 * 40], As_l[2][64 * 40];
  __shared__ __align__(16) _Float16 Bs_h[2][64 * 40], Bs_l[2][64 * 40];
  const int t = threadIdx.x;
  const int row0 = blockIdx.y * 64;
  const int col0 = blockIdx.x * 64;
  const int sr = t >> 2, sk = (t & 3) * 8;
  const int lane = t & 63, wv = t >> 6;
  const int wm = wv & 1, wn = wv >> 1;
  const int lm = lane & 15, qd = lane >> 4;
  f32x4 ac0[2][2] = {}, ac1[2][2] = {}, as0[2][2] = {}, as1[2][2] = {};
  const size_t abase = (size_t)(row0 + sr) * KCAT + sk;
  const size_t bbase = (size_t)(col0 + sr) * KCAT + sk;
  GEMM_LOOP
#pragma unroll
  for (int j = 0; j < 2; ++j) {
    int col = col0 + wn * 32 + j * 16 + lm;
    if (col <= 400) {
#pragma unroll
      for (int i = 0; i < 2; ++i)
#pragma unroll
        for (int r = 0; r < 4; ++r) {
          int row = row0 + wm * 32 + i * 16 + qd * 4 + r;
          int idx = row * NFREQ + col;
          float rr = ac0[i][j][r] + ac1[i][j][r] * LO_INV;   // Re (x256 scale)
          float ri = as0[i][j][r] + as1[i][j][r] * LO_INV;   // Im
          float nr = rr - beta * tppr[idx];
          float ni = ri - beta * tppi[idx];
          tppr[idx] = rr; tppi[idx] = ri;
          float den = sqrtf(nr * nr + ni * ni) + 1e-16f;
          float arv = nr / den, aiv = ni / den;
          float mg = mag[idx] * 256.0f;
          size_t ab = (size_t)row * KCAT;
          float v1 = mg * arv;
          _Float16 h1 = (_Float16)v1;
          A1h[ab + col] = h1;
          A1l[ab + col] = (_Float16)((v1 - (float)h1) * 2048.0f);
          float v2 = mg * aiv;
          _Float16 h2 = (_Float16)v2;
          A1h[ab + KHALF + col] = h2;
          A1l[ab + KHALF + col] = (_Float16)((v2 - (float)h2) * 2048.0f);
        }
    }
  }
}

// ---------------- final overlap-add (full y, once; exact divide) ----------------
__global__ void k_ola(const float* __restrict__ frames, const float* __restrict__ wsqs,
                      float* __restrict__ y) {
  int idx = blockIdx.x * blockDim.x + threadIdx.x;
  if (idx >= NB * LY) return;
  int b = idx / LY, j = idx - b * LY;
  int t1 = j / HOPSZ; if (t1 > TT - 1) t1 = TT - 1;
  int t0 = (j - (NFFT - HOPSZ)) / HOPSZ; if (t0 < 0) t0 = 0;
  const float* fb_ = frames + (size_t)b * TT * NFFT;
  float s = 0.f;
  for (int t = t0; t <= t1; ++t) s += fb_[t * NFFT + (j - t * HOPSZ)];
  y[idx] = s / wsqs[j];
}

// ---------------- epilogue: peak-normalize ----------------
__global__ void k_absmax(const float* __restrict__ y, float* __restrict__ peak) {
  __shared__ float red[256];
  int b = blockIdx.x;
  const float* yb = y + (size_t)b * LY + PADW;
  float mx = 0.f;
  for (int j = threadIdx.x; j < LOUTW; j += 256) mx = fmaxf(mx, fabsf(yb[j]));
  red[threadIdx.x] = mx;
  __syncthreads();
  for (int s2 = 128; s2 > 0; s2 >>= 1) {
    if (threadIdx.x < s2) red[threadIdx.x] = fmaxf(red[threadIdx.x], red[threadIdx.x + s2]);
    __syncthreads();
  }
  if (threadIdx.x == 0) peak[b] = red[0];
}

__global__ void k_scale(const float* __restrict__ y, const float* __restrict__ peak,
                        float* __restrict__ out, float target) {
  int idx = blockIdx.x * blockDim.x + threadIdx.x;
  if (idx >= NB * LOUTW) return;
  int b = idx / LOUTW, j = idx - b * LOUTW;
  out[idx] = y[(size_t)b * LY + PADW + j] * (target / peak[b]);
}

__global__ void k_zero2(float* __restrict__ a, float* __restrict__ b, int n) {
  int i = blockIdx.x * blockDim.x + threadIdx.x;
  if (i < n) { a[i] = 0.f; b[i] = 0.f; }
}

// ---------------- host ----------------
extern "C" void kernel_launch(void* const* d_in, const int* in_sizes, int n_in,
                              void* d_out, int out_size, void* d_ws, size_t ws_size,
                              hipStream_t stream) {
  const float* xmel = (const float*)d_in[0];   // (8, 80, 512) f32
  float* out = (float*)d_out;                  // (8, 1, 102200) f32

  char* p = (char*)d_ws;
  auto alloc = [&](size_t nbytes) -> void* {
    void* r = (void*)p;
    p += (nbytes + 255) & ~(size_t)255;
    return r;
  };
  float* mag  = (float*)alloc((size_t)NSPEC * 4);
  float* ar   = (float*)alloc((size_t)NSPEC * 4);
  float* ai   = (float*)alloc((size_t)NSPEC * 4);
  float* tpr  = (float*)alloc((size_t)NSPEC * 4);
  float* tpi  = (float*)alloc((size_t)NSPEC * 4);
  float* y    = (float*)alloc((size_t)NB * LY * 4);
  float* win  = (float*)alloc(NFFT * 4);
  float* wsqs = (float*)alloc((size_t)LY * 4);
  float* wsinv= (float*)alloc((size_t)LY * 4);
  float* fbT  = (float*)alloc((size_t)NMELS * NFREQ * 4);
  float* fw0  = (float*)alloc(NFREQ * 4);
  float* fw1  = (float*)alloc(NFREQ * 4);
  float* peak = (float*)alloc(NB * 4);
  int* fm0    = (int*)alloc(NFREQ * 4);
  int* mlo    = (int*)alloc(NMELS * 4);
  int* mhi    = (int*)alloc(NMELS * 4);
  float* frames = (float*)alloc((size_t)NROWS * NFFT * 4);
  float* spec0 = frames;  // alias: consumed by k_sgd before frames written
  _Float16* A1h = (_Float16*)alloc((size_t)NROWS * KCAT * 2);
  _Float16* A1l = (_Float16*)alloc((size_t)NROWS * KCAT * 2);
  _Float16* A2h = (_Float16*)alloc((size_t)NROWS * KCAT * 2);
  _Float16* A2l = (_Float16*)alloc((size_t)NROWS * KCAT * 2);
  _Float16* B1h = (_Float16*)alloc((size_t)NCOLS * KCAT * 2);
  _Float16* B1l = (_Float16*)alloc((size_t)NCOLS * KCAT * 2);
  _Float16* B2h = (_Float16*)alloc((size_t)NCOLS * KCAT * 2);
  _Float16* B2l = (_Float16*)alloc((size_t)NCOLS * KCAT * 2);

  if ((size_t)(p - (char*)d_ws) > ws_size) return;  // insufficient scratch

  // derived threefry keys (jax partitionable split)
  unsigned k1a, k1b, k2a, k2b, kra, krb, kia, kib;
  {
    unsigned o0, o1;
    tf2x32(0u, 1u, 0u, 0u, o0, o1); k1a = o0; k1b = o1;
    tf2x32(0u, 1u, 0u, 1u, o0, o1); k2a = o0; k2b = o1;
    tf2x32(k2a, k2b, 0u, 0u, o0, o1); kra = o0; krb = o1;
    tf2x32(k2a, k2b, 0u, 1u, o0, o1); kia = o0; kib = o1;
  }

  // init
  k_fb<<<2, 256, 0, stream>>>(fbT, fm0, fw0, fw1);
  k_ranges<<<1, 128, 0, stream>>>(fbT, mlo, mhi);
  k_wsq<<<(LY + 255) / 256, 256, 0, stream>>>(wsqs, wsinv, win);
  k_tabs1<<<(NCOLS * KCAT + 255) / 256, 256, 0, stream>>>(B1h, B1l);
  k_tabs2<<<(NCOLS * KCAT + 255) / 256, 256, 0, stream>>>(B2h, B2l);
  k_zero2<<<(NSPEC + 255) / 256, 256, 0, stream>>>(tpr, tpi, NSPEC);
  k_rand_spec<<<(NSPEC + 255) / 256, 256, 0, stream>>>(k1a, k1b, spec0);
  k_rand_ang<<<(NSPEC + 255) / 256, 256, 0, stream>>>(kra, krb, kia, kib, ar, ai);

  // InverseMelScale (1 wave per (b,t) row, register-resident)
  k_sgd<<<NROWS, 64, 0, stream>>>(spec0, xmel, fbT, mlo, mhi, fm0, fw0, fw1, mag);

  // iteration-0 A1 (layout [Re@0|Im@416], pads zeroed once)
  k_prep1<<<dim3(4, NROWS), 256, 0, stream>>>(mag, ar, ai, A1h, A1l);

  // Griffin-Lim: 3 dispatches per iteration
  const float beta = (float)(0.99 / 1.99);
  for (int it = 0; it < GLITERS; ++it) {
    k_mm1<<<dim3(7, 64), 256, 0, stream>>>(A1h, A1l, B1h, B1l, win, frames);
    k_olaprep<<<(NROWS * KHALF + 255) / 256, 256, 0, stream>>>(frames, wsinv, win, A2h, A2l);
    k_mm2<<<dim3(7, 64), 256, 0, stream>>>(A2h, A2l, B2h, B2l,
                                           mag, tpr, tpi, A1h, A1l, beta);
  }
  // final istft with final angles (A1 written by last k_mm2)
  k_mm1<<<dim3(7, 64), 256, 0, stream>>>(A1h, A1l, B1h, B1l, win, frames);
  k_ola<<<(NB * LY + 255) / 256, 256, 0, stream>>>(frames, wsqs, y);

  // normalize
  k_absmax<<<NB, 256, 0, stream>>>(y, peak);
  const float target = (float)pow(10.0, -0.1 / 20.0);
  k_scale<<<(NB * LOUTW + 255) / 256, 256, 0, stream>>>(y, peak, out, target);
}